// Round 10
// baseline (2050.302 us; speedup 1.0000x reference)
//
#include <hip/hip_runtime.h>
#include <hip/hip_bf16.h>
#include <math.h>

#define N_NODES 50000
#define E_EDGES 800000
#define NFEAT 16
#define EFEAT 8
#define HID 32
#define HEADS 4
#define HC 128
#define SCAN_NB ((N_NODES + 255) / 256)   // 196

typedef float f4v __attribute__((ext_vector_type(4)));

__device__ __forceinline__ float lrelu(float v) { return v > 0.f ? v : 0.2f * v; }
__device__ __forceinline__ float bflo(unsigned u) { return __uint_as_float(u << 16); }
__device__ __forceinline__ float bfhi(unsigned u) { return __uint_as_float(u & 0xffff0000u); }

// ---- K1: h = x @ W ; alpha_src/dst = einsum(h, aS/aD) per head ----
// xs staged as float4; BF16OUT stores h as bf16 (alpha still from fp32 acc).
template<int FIN, int HOUT, int H, bool BF16OUT>
__global__ void k1_gemm_alpha(const float* __restrict__ x, const float* __restrict__ W,
                              const float* __restrict__ aS, const float* __restrict__ aD,
                              void* __restrict__ hout, float* __restrict__ asrc,
                              float* __restrict__ adst, int n_nodes)
{
    constexpr int GROUPS = 256 / HOUT;
    constexpr int NPT = 4;
    constexpr int NPB = GROUPS * NPT;
    constexpr int F4 = FIN / 4;
    __shared__ __align__(16) f4v xs4[NPB * F4];
    const int tid = threadIdx.x;
    const int nb0 = blockIdx.x * NPB;
    for (int idx = tid; idx < NPB * F4; idx += 256) {
        int node = idx / F4, kq = idx % F4;
        int gn = nb0 + node;
        f4v v = {0.f, 0.f, 0.f, 0.f};
        if (gn < n_nodes) v = *(const f4v*)(x + (size_t)gn * FIN + kq * 4);
        xs4[node * F4 + kq] = v;
    }
    __syncthreads();
    const int c = tid % HOUT;
    const int g = tid / HOUT;
    const int head = c / HID;
    const int cc = c % HID;
    const float aSv = aS[head * HID + cc];
    const float aDv = aD[head * HID + cc];
    float acc[NPT];
#pragma unroll
    for (int i = 0; i < NPT; i++) acc[i] = 0.f;
    for (int kq = 0; kq < F4; kq++) {
        float w0 = W[(4 * kq + 0) * HOUT + c];
        float w1 = W[(4 * kq + 1) * HOUT + c];
        float w2 = W[(4 * kq + 2) * HOUT + c];
        float w3 = W[(4 * kq + 3) * HOUT + c];
#pragma unroll
        for (int i = 0; i < NPT; i++) {
            f4v xv = xs4[(g * NPT + i) * F4 + kq];
            acc[i] += w0 * xv.x + w1 * xv.y + w2 * xv.z + w3 * xv.w;
        }
    }
#pragma unroll
    for (int i = 0; i < NPT; i++) {
        int n = nb0 + g * NPT + i;
        bool ok = (n < n_nodes);
        float h = acc[i];
        if (ok) {
            if (BF16OUT)
                ((__hip_bfloat16*)hout)[(size_t)n * HOUT + c] = __float2bfloat16(h);
            else
                ((float*)hout)[(size_t)n * HOUT + c] = h;
        }
        float pa = h * aSv, pb = h * aDv;
#pragma unroll
        for (int off = 16; off >= 1; off >>= 1) {
            pa += __shfl_xor(pa, off, 32);
            pb += __shfl_xor(pb, off, 32);
        }
        if (ok && cc == 0) { asrc[n * H + head] = pa; adst[n * H + head] = pb; }
    }
}

// ---- CSR build: histogram -> 3-phase scan -> scatter ----
__global__ void kc_count(const int* __restrict__ ei1, int* __restrict__ cnt)
{
    int e = blockIdx.x * 256 + threadIdx.x;
    if (e >= E_EDGES) return;
    atomicAdd(&cnt[ei1[e]], 1);
}

__global__ __launch_bounds__(256) void kc_blocksum(const int* __restrict__ cnt,
                                                   int* __restrict__ bsum)
{
    __shared__ int sd[256];
    const int tid = threadIdx.x;
    int i = blockIdx.x * 256 + tid;
    int v = (i < N_NODES) ? cnt[i] : 0;
    sd[tid] = v;
    __syncthreads();
    for (int off = 128; off >= 1; off >>= 1) {
        if (tid < off) sd[tid] += sd[tid + off];
        __syncthreads();
    }
    if (tid == 0) bsum[blockIdx.x] = sd[0];
}

__global__ __launch_bounds__(256) void kc_scanbsum(const int* __restrict__ bsum,
                                                   int* __restrict__ bofs)
{
    __shared__ int sd[256];
    const int tid = threadIdx.x;
    int v = (tid < SCAN_NB) ? bsum[tid] : 0;
    sd[tid] = v;
    __syncthreads();
    for (int off = 1; off < 256; off <<= 1) {
        int u = (tid >= off) ? sd[tid - off] : 0;
        __syncthreads();
        sd[tid] += u;
        __syncthreads();
    }
    if (tid < SCAN_NB) bofs[tid] = sd[tid] - v;
}

__global__ __launch_bounds__(256) void kc_apply(const int* __restrict__ cnt,
                                                const int* __restrict__ bofs,
                                                int* __restrict__ rowptr,
                                                int* __restrict__ cur)
{
    __shared__ int sd[256];
    const int tid = threadIdx.x;
    int i = blockIdx.x * 256 + tid;
    int v = (i < N_NODES) ? cnt[i] : 0;
    sd[tid] = v;
    __syncthreads();
    for (int off = 1; off < 256; off <<= 1) {
        int u = (tid >= off) ? sd[tid - off] : 0;
        __syncthreads();
        sd[tid] += u;
        __syncthreads();
    }
    int excl = sd[tid] - v + bofs[blockIdx.x];
    if (i < N_NODES) { rowptr[i] = excl; cur[i] = excl; }
}

__global__ void kc_scatter(const int* __restrict__ ei0, const int* __restrict__ ei1,
                           int* __restrict__ cur, int* __restrict__ srcs)
{
    int e = blockIdx.x * 256 + threadIdx.x;
    if (e >= E_EDGES) return;
    int pos = atomicAdd(&cur[ei1[e]], 1);
    srcs[pos] = ei0[e];
}

// ---- fused aggregation: online segment-softmax + weighted sum + bias (+ELU) ----
// TPE lanes per node, 2 channels per lane. 4-way batched loads (R8 structure).
// BF16H: h gathers are bf16-packed (one uint per lane = 2 channels).
template<int H, int C, bool DO_ELU, bool BF16H>
__global__ __launch_bounds__(256) void k_aggr(
    const float* __restrict__ asrc, const float* __restrict__ adst,
    const void* __restrict__ hbuf, const int* __restrict__ rowptr,
    const int* __restrict__ deg, const int* __restrict__ srcs,
    const float* __restrict__ b, float* __restrict__ outp)
{
    constexpr int HCL = H * C;
    constexpr int TPE = HCL / 2;
    constexpr int NPB = 256 / TPE;
    const int t = threadIdx.x % TPE;
    const int n = blockIdx.x * NPB + threadIdx.x / TPE;
    if (n >= N_NODES) return;
    const int c0 = 2 * t;
    const int head = c0 / C;
    const float adstv = adst[n * H + head];
    const unsigned* hbu = (const unsigned*)hbuf;
    const float* hbf = (const float*)hbuf;
    // init with self-loop
    float m = lrelu(asrc[n * H + head] + adstv);
    float ssum = 1.f;
    float a0, a1;
    if (BF16H) {
        unsigned u = hbu[(size_t)n * TPE + t];
        a0 = bflo(u); a1 = bfhi(u);
    } else {
        float2 hv = *(const float2*)(hbf + (size_t)n * HCL + c0);
        a0 = hv.x; a1 = hv.y;
    }
    const int base = rowptr[n];
    const int dg = deg[n];
    int i = 0;
    for (; i + 4 <= dg; i += 4) {
        int s0 = srcs[base + i + 0];
        int s1 = srcs[base + i + 1];
        int s2 = srcs[base + i + 2];
        int s3 = srcs[base + i + 3];
        float sc[4];
        sc[0] = lrelu(asrc[s0 * H + head] + adstv);
        sc[1] = lrelu(asrc[s1 * H + head] + adstv);
        sc[2] = lrelu(asrc[s2 * H + head] + adstv);
        sc[3] = lrelu(asrc[s3 * H + head] + adstv);
        float hx[4], hy[4];
        if (BF16H) {
            unsigned u0 = hbu[(size_t)s0 * TPE + t];
            unsigned u1 = hbu[(size_t)s1 * TPE + t];
            unsigned u2 = hbu[(size_t)s2 * TPE + t];
            unsigned u3 = hbu[(size_t)s3 * TPE + t];
            hx[0] = bflo(u0); hy[0] = bfhi(u0);
            hx[1] = bflo(u1); hy[1] = bfhi(u1);
            hx[2] = bflo(u2); hy[2] = bfhi(u2);
            hx[3] = bflo(u3); hy[3] = bfhi(u3);
        } else {
            float2 h0 = *(const float2*)(hbf + (size_t)s0 * HCL + c0);
            float2 h1 = *(const float2*)(hbf + (size_t)s1 * HCL + c0);
            float2 h2 = *(const float2*)(hbf + (size_t)s2 * HCL + c0);
            float2 h3 = *(const float2*)(hbf + (size_t)s3 * HCL + c0);
            hx[0] = h0.x; hy[0] = h0.y;
            hx[1] = h1.x; hy[1] = h1.y;
            hx[2] = h2.x; hy[2] = h2.y;
            hx[3] = h3.x; hy[3] = h3.y;
        }
#pragma unroll
        for (int u = 0; u < 4; u++) {
            float scv = sc[u];
            float ex;
            if (scv > m) {
                float r = __expf(m - scv);
                ssum *= r; a0 *= r; a1 *= r;
                m = scv;
                ex = 1.f;
            } else {
                ex = __expf(scv - m);
            }
            ssum += ex;
            a0 += ex * hx[u];
            a1 += ex * hy[u];
        }
    }
    for (; i < dg; i++) {
        int s = srcs[base + i];
        float sc = lrelu(asrc[s * H + head] + adstv);
        float hxv, hyv;
        if (BF16H) {
            unsigned u = hbu[(size_t)s * TPE + t];
            hxv = bflo(u); hyv = bfhi(u);
        } else {
            float2 hs = *(const float2*)(hbf + (size_t)s * HCL + c0);
            hxv = hs.x; hyv = hs.y;
        }
        float ex;
        if (sc > m) {
            float r = __expf(m - sc);
            ssum *= r; a0 *= r; a1 *= r;
            m = sc;
            ex = 1.f;
        } else {
            ex = __expf(sc - m);
        }
        ssum += ex;
        a0 += ex * hxv;
        a1 += ex * hyv;
    }
    float inv = 1.f / (ssum + 1e-16f);
    float v0 = a0 * inv + b[c0];
    float v1 = a1 * inv + b[c0 + 1];
    if (DO_ELU) {
        v0 = v0 > 0.f ? v0 : __expf(v0) - 1.f;
        v1 = v1 > 0.f ? v1 : __expf(v1) - 1.f;
    }
    *(float2*)(outp + (size_t)n * HCL + c0) = make_float2(v0, v1);
}

// ---- K5a: node-level precompute for MLP layer 1 (bf16 output) ----
__global__ __launch_bounds__(256) void k5a_precomp(
    const float* __restrict__ h3, const float* __restrict__ Wm1,
    __hip_bfloat16* __restrict__ Pb)
{
    __shared__ __align__(16) float w[64 * 32];      // rows 0..63 of Wm1
    __shared__ __align__(16) float hsh[16][33];
    const int tid = threadIdx.x;
    for (int i = tid; i < 64 * 32; i += 256) w[i] = Wm1[i];
    const int nb0 = blockIdx.x * 16;
    for (int idx = tid; idx < 16 * 32; idx += 256) {
        int node = idx / 32, k = idx % 32;
        int gn = nb0 + node;
        hsh[node][k] = (gn < N_NODES) ? h3[gn * 32 + k] : 0.f;
    }
    __syncthreads();
    const int c = tid % 64;           // output channel 0..63
    const int part = c / 32;          // 0 -> W1a, 1 -> W1b
    const int j = c % 32;
    for (int ln = tid / 64; ln < 16; ln += 4) {
        int gn = nb0 + ln;
        if (gn >= N_NODES) break;
        float sum = 0.f;
#pragma unroll
        for (int k = 0; k < 32; k++)
            sum += hsh[ln][k] * w[(part * 32 + k) * 32 + j];
        Pb[(size_t)gn * 64 + c] = __float2bfloat16(sum);
    }
}

// ---- K5b: per-edge MLP using precomputed bf16 P ----
__global__ __launch_bounds__(256) void k5b_mlp(
                       const int* __restrict__ ei0, const int* __restrict__ ei1,
                       const __hip_bfloat16* __restrict__ Pb, const float* __restrict__ ea,
                       const float* __restrict__ Wm1, const float* __restrict__ bm1,
                       const float* __restrict__ Wm2, const float* __restrict__ bm2,
                       const float* __restrict__ Wm3, const float* __restrict__ bm3,
                       float* __restrict__ out)
{
    __shared__ __align__(16) float w1c[8 * 32];
    __shared__ __align__(16) float w2[32 * 32];
    __shared__ __align__(16) float w3s[32], b1s[32], b2s[32];
    __shared__ float b3s;
    const int tid = threadIdx.x;
    if (tid < 8 * 32) w1c[tid] = Wm1[64 * 32 + tid];
    for (int i = tid; i < 32 * 32; i += 256) w2[i] = Wm2[i];
    if (tid < 32) { w3s[tid] = Wm3[tid]; b1s[tid] = bm1[tid]; b2s[tid] = bm2[tid]; }
    if (tid == 0) b3s = bm3[0];
    __syncthreads();
    const int e = blockIdx.x * 256 + tid;
    if (e >= E_EDGES) return;
    const int s = ei0[e], d = ei1[e];

    float z1[32];
#pragma unroll
    for (int j = 0; j < 32; j++) z1[j] = b1s[j];

    const f4v* eav = (const f4v*)(ea + (size_t)e * 8);
#pragma unroll
    for (int kq = 0; kq < 2; kq++) {
        f4v v = __builtin_nontemporal_load(&eav[kq]);
        const float* wrow = &w1c[(kq * 4) * 32];
#pragma unroll
        for (int j = 0; j < 32; j++) z1[j] += v.x * wrow[0 * 32 + j];
#pragma unroll
        for (int j = 0; j < 32; j++) z1[j] += v.y * wrow[1 * 32 + j];
#pragma unroll
        for (int j = 0; j < 32; j++) z1[j] += v.z * wrow[2 * 32 + j];
#pragma unroll
        for (int j = 0; j < 32; j++) z1[j] += v.w * wrow[3 * 32 + j];
    }
    const uint4* ps4 = (const uint4*)(Pb + (size_t)s * 64);
    const uint4* pd4 = (const uint4*)(Pb + (size_t)d * 64 + 32);
#pragma unroll
    for (int q = 0; q < 4; q++) {
        uint4 a = ps4[q];
        uint4 b = pd4[q];
        z1[8 * q + 0] += bflo(a.x) + bflo(b.x);
        z1[8 * q + 1] += bfhi(a.x) + bfhi(b.x);
        z1[8 * q + 2] += bflo(a.y) + bflo(b.y);
        z1[8 * q + 3] += bfhi(a.y) + bfhi(b.y);
        z1[8 * q + 4] += bflo(a.z) + bflo(b.z);
        z1[8 * q + 5] += bfhi(a.z) + bfhi(b.z);
        z1[8 * q + 6] += bflo(a.w) + bflo(b.w);
        z1[8 * q + 7] += bfhi(a.w) + bfhi(b.w);
    }
#pragma unroll
    for (int j = 0; j < 32; j++) z1[j] = z1[j] > 0.f ? z1[j] : 0.f;

    float acc2[32];
#pragma unroll
    for (int j = 0; j < 32; j++) acc2[j] = b2s[j];
#pragma unroll
    for (int k = 0; k < 32; k++) {
        float zk = z1[k];
        const f4v* w2r = (const f4v*)&w2[k * 32];
#pragma unroll
        for (int q = 0; q < 8; q++) {
            f4v w = w2r[q];
            acc2[4 * q + 0] += zk * w.x;
            acc2[4 * q + 1] += zk * w.y;
            acc2[4 * q + 2] += zk * w.z;
            acc2[4 * q + 3] += zk * w.w;
        }
    }
    float z3 = b3s;
#pragma unroll
    for (int j = 0; j < 32; j++) z3 += (acc2[j] > 0.f ? acc2[j] : 0.f) * w3s[j];

    float r = (z3 > 20.f) ? z3 : log1pf(__expf(z3));
    __builtin_nontemporal_store(r, &out[e]);
}

extern "C" void kernel_launch(void* const* d_in, const int* in_sizes, int n_in,
                              void* d_out, int out_size, void* d_ws, size_t ws_size,
                              hipStream_t stream)
{
    const float* x   = (const float*)d_in[0];
    const int*   ei  = (const int*)d_in[1];
    const int*   ei0 = ei;
    const int*   ei1 = ei + E_EDGES;
    const float* ea  = (const float*)d_in[2];
    const float* W1  = (const float*)d_in[3];
    const float* aS1 = (const float*)d_in[4];
    const float* aD1 = (const float*)d_in[5];
    const float* b1  = (const float*)d_in[6];
    const float* W2  = (const float*)d_in[7];
    const float* aS2 = (const float*)d_in[8];
    const float* aD2 = (const float*)d_in[9];
    const float* b2  = (const float*)d_in[10];
    const float* W3  = (const float*)d_in[11];
    const float* aS3 = (const float*)d_in[12];
    const float* aD3 = (const float*)d_in[13];
    const float* b3  = (const float*)d_in[14];
    const float* Wm1 = (const float*)d_in[15];
    const float* bm1 = (const float*)d_in[16];
    const float* Wm2 = (const float*)d_in[17];
    const float* bm2 = (const float*)d_in[18];
    const float* Wm3 = (const float*)d_in[19];
    const float* bm3 = (const float*)d_in[20];

    float* ws = (float*)d_ws;
    float* bufA = ws;                                    // h (bf16 L1/L2, f32 L3) / later Pb
    float* bufB = bufA + (size_t)N_NODES * HC;           // [N,128] layer output (f32)
    float* asrc = bufB + (size_t)N_NODES * HC;           // [N,4]
    float* adst = asrc + (size_t)N_NODES * HEADS;        // [N,4]
    int* cnt    = (int*)(adst + (size_t)N_NODES * HEADS);// [N] in-degree (no self-loop)
    int* rowptr = cnt + N_NODES;                         // [N]
    int* cur    = rowptr + N_NODES;                      // [N]
    int* srcs   = cur + N_NODES;                         // [E]
    int* bsum   = srcs + E_EDGES;                        // [SCAN_NB]
    int* bofs   = bsum + 256;                            // [SCAN_NB]

    float* out = (float*)d_out;

    // ---------------- CSR build (once; shared by all 3 layers) ----------------
    hipMemsetAsync(cnt, 0, (size_t)N_NODES * sizeof(int), stream);
    kc_count<<<(E_EDGES + 255) / 256, 256, 0, stream>>>(ei1, cnt);
    kc_blocksum<<<SCAN_NB, 256, 0, stream>>>(cnt, bsum);
    kc_scanbsum<<<1, 256, 0, stream>>>(bsum, bofs);
    kc_apply<<<SCAN_NB, 256, 0, stream>>>(cnt, bofs, rowptr, cur);
    kc_scatter<<<(E_EDGES + 255) / 256, 256, 0, stream>>>(ei0, ei1, cur, srcs);

    // ---------------- Layer 1: x[N,16] -> bufB[N,128] (ELU), bf16 h ----------------
    k1_gemm_alpha<NFEAT, HC, HEADS, true><<<(N_NODES + 7) / 8, 256, 0, stream>>>(
        x, W1, aS1, aD1, bufA, asrc, adst, N_NODES);
    k_aggr<HEADS, HID, true, true><<<(N_NODES + 3) / 4, 256, 0, stream>>>(
        asrc, adst, bufA, rowptr, cnt, srcs, b1, bufB);

    // ---------------- Layer 2: bufB[N,128] -> bufB[N,128] (ELU), bf16 h ----------------
    k1_gemm_alpha<HC, HC, HEADS, true><<<(N_NODES + 7) / 8, 256, 0, stream>>>(
        bufB, W2, aS2, aD2, bufA, asrc, adst, N_NODES);
    k_aggr<HEADS, HID, true, true><<<(N_NODES + 3) / 4, 256, 0, stream>>>(
        asrc, adst, bufA, rowptr, cnt, srcs, b2, bufB);

    // ---------------- Layer 3: bufB[N,128] -> bufB[N,32] (no act, H=1), fp32 ----------------
    k1_gemm_alpha<HC, HID, 1, false><<<(N_NODES + 31) / 32, 256, 0, stream>>>(
        bufB, W3, aS3, aD3, bufA, asrc, adst, N_NODES);
    k_aggr<1, HID, false, false><<<(N_NODES + 15) / 16, 256, 0, stream>>>(
        asrc, adst, bufA, rowptr, cnt, srcs, b3, bufB);

    // ---------------- Edge MLP: node precompute (bf16), then per-edge ----------------
    __hip_bfloat16* Pb = (__hip_bfloat16*)bufA;   // bufA free after layer 3
    k5a_precomp<<<(N_NODES + 15) / 16, 256, 0, stream>>>(bufB, Wm1, Pb);
    k5b_mlp<<<(E_EDGES + 255) / 256, 256, 0, stream>>>(
        ei0, ei1, Pb, ea, Wm1, bm1, Wm2, bm2, Wm3, bm3, out);
}

// Round 11
// 410.082 us; speedup vs baseline: 4.9997x; 4.9997x over previous
//
#include <hip/hip_runtime.h>
#include <hip/hip_bf16.h>
#include <math.h>

#define N_NODES 50000
#define E_EDGES 800000
#define NFEAT 16
#define EFEAT 8
#define HID 32
#define HEADS 4
#define HC 128
#define SCAN_NB ((N_NODES + 255) / 256)   // 196

typedef float f4v __attribute__((ext_vector_type(4)));

__device__ __forceinline__ float lrelu(float v) { return v > 0.f ? v : 0.2f * v; }
__device__ __forceinline__ float bflo(unsigned u) { return __uint_as_float(u << 16); }
__device__ __forceinline__ float bfhi(unsigned u) { return __uint_as_float(u & 0xffff0000u); }

// ---- K1: h = x @ W ; alpha_src/dst = einsum(h, aS/aD) per head ----
// R9-proven scalar structure (scalar LDS staging, one W row per k iteration).
// Only change vs R9: optional bf16 store of h (alpha still from fp32 acc).
template<int FIN, int HOUT, int H, bool BF16OUT>
__global__ void k1_gemm_alpha(const float* __restrict__ x, const float* __restrict__ W,
                              const float* __restrict__ aS, const float* __restrict__ aD,
                              void* __restrict__ hout, float* __restrict__ asrc,
                              float* __restrict__ adst, int n_nodes)
{
    constexpr int GROUPS = 256 / HOUT;
    constexpr int NPT = 4;
    constexpr int NPB = GROUPS * NPT;
    __shared__ float xs[NPB * (FIN + 1)];
    const int tid = threadIdx.x;
    const int nb0 = blockIdx.x * NPB;
    for (int idx = tid; idx < NPB * FIN; idx += 256) {
        int node = idx / FIN, k = idx % FIN;
        int gn = nb0 + node;
        xs[node * (FIN + 1) + k] = (gn < n_nodes) ? x[(size_t)gn * FIN + k] : 0.f;
    }
    __syncthreads();
    const int c = tid % HOUT;
    const int g = tid / HOUT;
    const int head = c / HID;
    const int cc = c % HID;
    const float aSv = aS[head * HID + cc];
    const float aDv = aD[head * HID + cc];
    float acc[NPT];
#pragma unroll
    for (int i = 0; i < NPT; i++) acc[i] = 0.f;
    for (int k = 0; k < FIN; k++) {
        float w = W[k * HOUT + c];
#pragma unroll
        for (int i = 0; i < NPT; i++)
            acc[i] += w * xs[(g * NPT + i) * (FIN + 1) + k];
    }
#pragma unroll
    for (int i = 0; i < NPT; i++) {
        int n = nb0 + g * NPT + i;
        bool ok = (n < n_nodes);
        float h = acc[i];
        if (ok) {
            if (BF16OUT)
                ((__hip_bfloat16*)hout)[(size_t)n * HOUT + c] = __float2bfloat16(h);
            else
                ((float*)hout)[(size_t)n * HOUT + c] = h;
        }
        float pa = h * aSv, pb = h * aDv;
#pragma unroll
        for (int off = 16; off >= 1; off >>= 1) {
            pa += __shfl_xor(pa, off, 32);
            pb += __shfl_xor(pb, off, 32);
        }
        if (ok && cc == 0) { asrc[n * H + head] = pa; adst[n * H + head] = pb; }
    }
}

// ---- CSR build: histogram -> 3-phase scan -> scatter ----
__global__ void kc_count(const int* __restrict__ ei1, int* __restrict__ cnt)
{
    int e = blockIdx.x * 256 + threadIdx.x;
    if (e >= E_EDGES) return;
    atomicAdd(&cnt[ei1[e]], 1);
}

__global__ __launch_bounds__(256) void kc_blocksum(const int* __restrict__ cnt,
                                                   int* __restrict__ bsum)
{
    __shared__ int sd[256];
    const int tid = threadIdx.x;
    int i = blockIdx.x * 256 + tid;
    int v = (i < N_NODES) ? cnt[i] : 0;
    sd[tid] = v;
    __syncthreads();
    for (int off = 128; off >= 1; off >>= 1) {
        if (tid < off) sd[tid] += sd[tid + off];
        __syncthreads();
    }
    if (tid == 0) bsum[blockIdx.x] = sd[0];
}

__global__ __launch_bounds__(256) void kc_scanbsum(const int* __restrict__ bsum,
                                                   int* __restrict__ bofs)
{
    __shared__ int sd[256];
    const int tid = threadIdx.x;
    int v = (tid < SCAN_NB) ? bsum[tid] : 0;
    sd[tid] = v;
    __syncthreads();
    for (int off = 1; off < 256; off <<= 1) {
        int u = (tid >= off) ? sd[tid - off] : 0;
        __syncthreads();
        sd[tid] += u;
        __syncthreads();
    }
    if (tid < SCAN_NB) bofs[tid] = sd[tid] - v;
}

__global__ __launch_bounds__(256) void kc_apply(const int* __restrict__ cnt,
                                                const int* __restrict__ bofs,
                                                int* __restrict__ rowptr,
                                                int* __restrict__ cur)
{
    __shared__ int sd[256];
    const int tid = threadIdx.x;
    int i = blockIdx.x * 256 + tid;
    int v = (i < N_NODES) ? cnt[i] : 0;
    sd[tid] = v;
    __syncthreads();
    for (int off = 1; off < 256; off <<= 1) {
        int u = (tid >= off) ? sd[tid - off] : 0;
        __syncthreads();
        sd[tid] += u;
        __syncthreads();
    }
    int excl = sd[tid] - v + bofs[blockIdx.x];
    if (i < N_NODES) { rowptr[i] = excl; cur[i] = excl; }
}

__global__ void kc_scatter(const int* __restrict__ ei0, const int* __restrict__ ei1,
                           int* __restrict__ cur, int* __restrict__ srcs)
{
    int e = blockIdx.x * 256 + threadIdx.x;
    if (e >= E_EDGES) return;
    int pos = atomicAdd(&cur[ei1[e]], 1);
    srcs[pos] = ei0[e];
}

// ---- fused aggregation: online segment-softmax + weighted sum + bias (+ELU) ----
// TPE lanes per node, 2 channels per lane. 4-way batched loads (R8 structure).
// BF16H: h gathers are bf16-packed (one uint per lane = 2 channels).
template<int H, int C, bool DO_ELU, bool BF16H>
__global__ __launch_bounds__(256) void k_aggr(
    const float* __restrict__ asrc, const float* __restrict__ adst,
    const void* __restrict__ hbuf, const int* __restrict__ rowptr,
    const int* __restrict__ deg, const int* __restrict__ srcs,
    const float* __restrict__ b, float* __restrict__ outp)
{
    constexpr int HCL = H * C;
    constexpr int TPE = HCL / 2;
    constexpr int NPB = 256 / TPE;
    const int t = threadIdx.x % TPE;
    const int n = blockIdx.x * NPB + threadIdx.x / TPE;
    if (n >= N_NODES) return;
    const int c0 = 2 * t;
    const int head = c0 / C;
    const float adstv = adst[n * H + head];
    const unsigned* hbu = (const unsigned*)hbuf;
    const float* hbf = (const float*)hbuf;
    // init with self-loop
    float m = lrelu(asrc[n * H + head] + adstv);
    float ssum = 1.f;
    float a0, a1;
    if (BF16H) {
        unsigned u = hbu[(size_t)n * TPE + t];
        a0 = bflo(u); a1 = bfhi(u);
    } else {
        float2 hv = *(const float2*)(hbf + (size_t)n * HCL + c0);
        a0 = hv.x; a1 = hv.y;
    }
    const int base = rowptr[n];
    const int dg = deg[n];
    int i = 0;
    for (; i + 4 <= dg; i += 4) {
        int s0 = srcs[base + i + 0];
        int s1 = srcs[base + i + 1];
        int s2 = srcs[base + i + 2];
        int s3 = srcs[base + i + 3];
        float sc[4];
        sc[0] = lrelu(asrc[s0 * H + head] + adstv);
        sc[1] = lrelu(asrc[s1 * H + head] + adstv);
        sc[2] = lrelu(asrc[s2 * H + head] + adstv);
        sc[3] = lrelu(asrc[s3 * H + head] + adstv);
        float hx[4], hy[4];
        if (BF16H) {
            unsigned u0 = hbu[(size_t)s0 * TPE + t];
            unsigned u1 = hbu[(size_t)s1 * TPE + t];
            unsigned u2 = hbu[(size_t)s2 * TPE + t];
            unsigned u3 = hbu[(size_t)s3 * TPE + t];
            hx[0] = bflo(u0); hy[0] = bfhi(u0);
            hx[1] = bflo(u1); hy[1] = bfhi(u1);
            hx[2] = bflo(u2); hy[2] = bfhi(u2);
            hx[3] = bflo(u3); hy[3] = bfhi(u3);
        } else {
            float2 h0 = *(const float2*)(hbf + (size_t)s0 * HCL + c0);
            float2 h1 = *(const float2*)(hbf + (size_t)s1 * HCL + c0);
            float2 h2 = *(const float2*)(hbf + (size_t)s2 * HCL + c0);
            float2 h3 = *(const float2*)(hbf + (size_t)s3 * HCL + c0);
            hx[0] = h0.x; hy[0] = h0.y;
            hx[1] = h1.x; hy[1] = h1.y;
            hx[2] = h2.x; hy[2] = h2.y;
            hx[3] = h3.x; hy[3] = h3.y;
        }
#pragma unroll
        for (int u = 0; u < 4; u++) {
            float scv = sc[u];
            float ex;
            if (scv > m) {
                float r = __expf(m - scv);
                ssum *= r; a0 *= r; a1 *= r;
                m = scv;
                ex = 1.f;
            } else {
                ex = __expf(scv - m);
            }
            ssum += ex;
            a0 += ex * hx[u];
            a1 += ex * hy[u];
        }
    }
    for (; i < dg; i++) {
        int s = srcs[base + i];
        float sc = lrelu(asrc[s * H + head] + adstv);
        float hxv, hyv;
        if (BF16H) {
            unsigned u = hbu[(size_t)s * TPE + t];
            hxv = bflo(u); hyv = bfhi(u);
        } else {
            float2 hs = *(const float2*)(hbf + (size_t)s * HCL + c0);
            hxv = hs.x; hyv = hs.y;
        }
        float ex;
        if (sc > m) {
            float r = __expf(m - sc);
            ssum *= r; a0 *= r; a1 *= r;
            m = sc;
            ex = 1.f;
        } else {
            ex = __expf(sc - m);
        }
        ssum += ex;
        a0 += ex * hxv;
        a1 += ex * hyv;
    }
    float inv = 1.f / (ssum + 1e-16f);
    float v0 = a0 * inv + b[c0];
    float v1 = a1 * inv + b[c0 + 1];
    if (DO_ELU) {
        v0 = v0 > 0.f ? v0 : __expf(v0) - 1.f;
        v1 = v1 > 0.f ? v1 : __expf(v1) - 1.f;
    }
    *(float2*)(outp + (size_t)n * HCL + c0) = make_float2(v0, v1);
}

// ---- K5a: node-level precompute for MLP layer 1 (bf16 output) ----
__global__ __launch_bounds__(256) void k5a_precomp(
    const float* __restrict__ h3, const float* __restrict__ Wm1,
    __hip_bfloat16* __restrict__ Pb)
{
    __shared__ __align__(16) float w[64 * 32];      // rows 0..63 of Wm1
    __shared__ __align__(16) float hsh[16][33];
    const int tid = threadIdx.x;
    for (int i = tid; i < 64 * 32; i += 256) w[i] = Wm1[i];
    const int nb0 = blockIdx.x * 16;
    for (int idx = tid; idx < 16 * 32; idx += 256) {
        int node = idx / 32, k = idx % 32;
        int gn = nb0 + node;
        hsh[node][k] = (gn < N_NODES) ? h3[gn * 32 + k] : 0.f;
    }
    __syncthreads();
    const int c = tid % 64;           // output channel 0..63
    const int part = c / 32;          // 0 -> W1a, 1 -> W1b
    const int j = c % 32;
    for (int ln = tid / 64; ln < 16; ln += 4) {
        int gn = nb0 + ln;
        if (gn >= N_NODES) break;
        float sum = 0.f;
#pragma unroll
        for (int k = 0; k < 32; k++)
            sum += hsh[ln][k] * w[(part * 32 + k) * 32 + j];
        Pb[(size_t)gn * 64 + c] = __float2bfloat16(sum);
    }
}

// ---- K5b: per-edge MLP using precomputed bf16 P ----
__global__ __launch_bounds__(256) void k5b_mlp(
                       const int* __restrict__ ei0, const int* __restrict__ ei1,
                       const __hip_bfloat16* __restrict__ Pb, const float* __restrict__ ea,
                       const float* __restrict__ Wm1, const float* __restrict__ bm1,
                       const float* __restrict__ Wm2, const float* __restrict__ bm2,
                       const float* __restrict__ Wm3, const float* __restrict__ bm3,
                       float* __restrict__ out)
{
    __shared__ __align__(16) float w1c[8 * 32];
    __shared__ __align__(16) float w2[32 * 32];
    __shared__ __align__(16) float w3s[32], b1s[32], b2s[32];
    __shared__ float b3s;
    const int tid = threadIdx.x;
    if (tid < 8 * 32) w1c[tid] = Wm1[64 * 32 + tid];
    for (int i = tid; i < 32 * 32; i += 256) w2[i] = Wm2[i];
    if (tid < 32) { w3s[tid] = Wm3[tid]; b1s[tid] = bm1[tid]; b2s[tid] = bm2[tid]; }
    if (tid == 0) b3s = bm3[0];
    __syncthreads();
    const int e = blockIdx.x * 256 + tid;
    if (e >= E_EDGES) return;
    const int s = ei0[e], d = ei1[e];

    float z1[32];
#pragma unroll
    for (int j = 0; j < 32; j++) z1[j] = b1s[j];

    const f4v* eav = (const f4v*)(ea + (size_t)e * 8);
#pragma unroll
    for (int kq = 0; kq < 2; kq++) {
        f4v v = __builtin_nontemporal_load(&eav[kq]);
        const float* wrow = &w1c[(kq * 4) * 32];
#pragma unroll
        for (int j = 0; j < 32; j++) z1[j] += v.x * wrow[0 * 32 + j];
#pragma unroll
        for (int j = 0; j < 32; j++) z1[j] += v.y * wrow[1 * 32 + j];
#pragma unroll
        for (int j = 0; j < 32; j++) z1[j] += v.z * wrow[2 * 32 + j];
#pragma unroll
        for (int j = 0; j < 32; j++) z1[j] += v.w * wrow[3 * 32 + j];
    }
    const uint4* ps4 = (const uint4*)(Pb + (size_t)s * 64);
    const uint4* pd4 = (const uint4*)(Pb + (size_t)d * 64 + 32);
#pragma unroll
    for (int q = 0; q < 4; q++) {
        uint4 a = ps4[q];
        uint4 b = pd4[q];
        z1[8 * q + 0] += bflo(a.x) + bflo(b.x);
        z1[8 * q + 1] += bfhi(a.x) + bfhi(b.x);
        z1[8 * q + 2] += bflo(a.y) + bflo(b.y);
        z1[8 * q + 3] += bfhi(a.y) + bfhi(b.y);
        z1[8 * q + 4] += bflo(a.z) + bflo(b.z);
        z1[8 * q + 5] += bfhi(a.z) + bfhi(b.z);
        z1[8 * q + 6] += bflo(a.w) + bflo(b.w);
        z1[8 * q + 7] += bfhi(a.w) + bfhi(b.w);
    }
#pragma unroll
    for (int j = 0; j < 32; j++) z1[j] = z1[j] > 0.f ? z1[j] : 0.f;

    float acc2[32];
#pragma unroll
    for (int j = 0; j < 32; j++) acc2[j] = b2s[j];
#pragma unroll
    for (int k = 0; k < 32; k++) {
        float zk = z1[k];
        const f4v* w2r = (const f4v*)&w2[k * 32];
#pragma unroll
        for (int q = 0; q < 8; q++) {
            f4v w = w2r[q];
            acc2[4 * q + 0] += zk * w.x;
            acc2[4 * q + 1] += zk * w.y;
            acc2[4 * q + 2] += zk * w.z;
            acc2[4 * q + 3] += zk * w.w;
        }
    }
    float z3 = b3s;
#pragma unroll
    for (int j = 0; j < 32; j++) z3 += (acc2[j] > 0.f ? acc2[j] : 0.f) * w3s[j];

    float r = (z3 > 20.f) ? z3 : log1pf(__expf(z3));
    __builtin_nontemporal_store(r, &out[e]);
}

extern "C" void kernel_launch(void* const* d_in, const int* in_sizes, int n_in,
                              void* d_out, int out_size, void* d_ws, size_t ws_size,
                              hipStream_t stream)
{
    const float* x   = (const float*)d_in[0];
    const int*   ei  = (const int*)d_in[1];
    const int*   ei0 = ei;
    const int*   ei1 = ei + E_EDGES;
    const float* ea  = (const float*)d_in[2];
    const float* W1  = (const float*)d_in[3];
    const float* aS1 = (const float*)d_in[4];
    const float* aD1 = (const float*)d_in[5];
    const float* b1  = (const float*)d_in[6];
    const float* W2  = (const float*)d_in[7];
    const float* aS2 = (const float*)d_in[8];
    const float* aD2 = (const float*)d_in[9];
    const float* b2  = (const float*)d_in[10];
    const float* W3  = (const float*)d_in[11];
    const float* aS3 = (const float*)d_in[12];
    const float* aD3 = (const float*)d_in[13];
    const float* b3  = (const float*)d_in[14];
    const float* Wm1 = (const float*)d_in[15];
    const float* bm1 = (const float*)d_in[16];
    const float* Wm2 = (const float*)d_in[17];
    const float* bm2 = (const float*)d_in[18];
    const float* Wm3 = (const float*)d_in[19];
    const float* bm3 = (const float*)d_in[20];

    float* ws = (float*)d_ws;
    float* bufA = ws;                                    // h (bf16 L1/L2, f32 L3) / later Pb
    float* bufB = bufA + (size_t)N_NODES * HC;           // [N,128] layer output (f32)
    float* asrc = bufB + (size_t)N_NODES * HC;           // [N,4]
    float* adst = asrc + (size_t)N_NODES * HEADS;        // [N,4]
    int* cnt    = (int*)(adst + (size_t)N_NODES * HEADS);// [N] in-degree (no self-loop)
    int* rowptr = cnt + N_NODES;                         // [N]
    int* cur    = rowptr + N_NODES;                      // [N]
    int* srcs   = cur + N_NODES;                         // [E]
    int* bsum   = srcs + E_EDGES;                        // [SCAN_NB]
    int* bofs   = bsum + 256;                            // [SCAN_NB]

    float* out = (float*)d_out;

    // ---------------- CSR build (once; shared by all 3 layers) ----------------
    hipMemsetAsync(cnt, 0, (size_t)N_NODES * sizeof(int), stream);
    kc_count<<<(E_EDGES + 255) / 256, 256, 0, stream>>>(ei1, cnt);
    kc_blocksum<<<SCAN_NB, 256, 0, stream>>>(cnt, bsum);
    kc_scanbsum<<<1, 256, 0, stream>>>(bsum, bofs);
    kc_apply<<<SCAN_NB, 256, 0, stream>>>(cnt, bofs, rowptr, cur);
    kc_scatter<<<(E_EDGES + 255) / 256, 256, 0, stream>>>(ei0, ei1, cur, srcs);

    // ---------------- Layer 1: x[N,16] -> bufB[N,128] (ELU), bf16 h ----------------
    k1_gemm_alpha<NFEAT, HC, HEADS, true><<<(N_NODES + 7) / 8, 256, 0, stream>>>(
        x, W1, aS1, aD1, bufA, asrc, adst, N_NODES);
    k_aggr<HEADS, HID, true, true><<<(N_NODES + 3) / 4, 256, 0, stream>>>(
        asrc, adst, bufA, rowptr, cnt, srcs, b1, bufB);

    // ---------------- Layer 2: bufB[N,128] -> bufB[N,128] (ELU), bf16 h ----------------
    k1_gemm_alpha<HC, HC, HEADS, true><<<(N_NODES + 7) / 8, 256, 0, stream>>>(
        bufB, W2, aS2, aD2, bufA, asrc, adst, N_NODES);
    k_aggr<HEADS, HID, true, true><<<(N_NODES + 3) / 4, 256, 0, stream>>>(
        asrc, adst, bufA, rowptr, cnt, srcs, b2, bufB);

    // ---------------- Layer 3: bufB[N,128] -> bufB[N,32] (no act, H=1), fp32 ----------------
    k1_gemm_alpha<HC, HID, 1, false><<<(N_NODES + 31) / 32, 256, 0, stream>>>(
        bufB, W3, aS3, aD3, bufA, asrc, adst, N_NODES);
    k_aggr<1, HID, false, false><<<(N_NODES + 15) / 16, 256, 0, stream>>>(
        asrc, adst, bufA, rowptr, cnt, srcs, b3, bufB);

    // ---------------- Edge MLP: node precompute (bf16), then per-edge ----------------
    __hip_bfloat16* Pb = (__hip_bfloat16*)bufA;   // bufA free after layer 3
    k5a_precomp<<<(N_NODES + 15) / 16, 256, 0, stream>>>(bufB, Wm1, Pb);
    k5b_mlp<<<(E_EDGES + 255) / 256, 256, 0, stream>>>(
        ei0, ei1, Pb, ea, Wm1, bm1, Wm2, bm2, Wm3, bm3, out);
}

// Round 12
// 392.846 us; speedup vs baseline: 5.2191x; 1.0439x over previous
//
#include <hip/hip_runtime.h>
#include <hip/hip_bf16.h>
#include <math.h>

#define N_NODES 50000
#define E_EDGES 800000
#define NFEAT 16
#define EFEAT 8
#define HID 32
#define HEADS 4
#define HC 128
#define SCAN_NB ((N_NODES + 255) / 256)   // 196

typedef float f4v __attribute__((ext_vector_type(4)));

__device__ __forceinline__ float lrelu(float v) { return v > 0.f ? v : 0.2f * v; }
__device__ __forceinline__ float bflo(unsigned u) { return __uint_as_float(u << 16); }
__device__ __forceinline__ float bfhi(unsigned u) { return __uint_as_float(u & 0xffff0000u); }

// ---- K1: h = x @ W ; alpha_src/dst = einsum(h, aS/aD) per head ----
// HOUT>=64: per-wave node group is wave-uniform -> x rows read via the SCALAR
// path (readfirstlane + uniform global loads -> s_load), no LDS, no barrier.
// HOUT==32: groups straddle waves -> keep proven LDS staging path.
template<int FIN, int HOUT, int H, bool BF16OUT>
__global__ void k1_gemm_alpha(const float* __restrict__ x, const float* __restrict__ W,
                              const float* __restrict__ aS, const float* __restrict__ aD,
                              void* __restrict__ hout, float* __restrict__ asrc,
                              float* __restrict__ adst, int n_nodes)
{
    constexpr int GROUPS = 256 / HOUT;
    constexpr int NPT = 4;
    constexpr int NPB = GROUPS * NPT;
    constexpr bool SCALARX = (HOUT >= 64);
    __shared__ float xs[SCALARX ? 1 : NPB * (FIN + 1)];
    const int tid = threadIdx.x;
    const int nb0 = blockIdx.x * NPB;
    const int c = tid % HOUT;
    const int g = tid / HOUT;

    if constexpr (!SCALARX) {
        for (int idx = tid; idx < NPB * FIN; idx += 256) {
            int node = idx / FIN, k = idx % FIN;
            int gn = nb0 + node;
            xs[node * (FIN + 1) + k] = (gn < n_nodes) ? x[(size_t)gn * FIN + k] : 0.f;
        }
        __syncthreads();
    }

    const int head = c / HID;
    const int cc = c % HID;
    const float aSv = aS[head * HID + cc];
    const float aDv = aD[head * HID + cc];
    float acc[NPT];
#pragma unroll
    for (int i = 0; i < NPT; i++) acc[i] = 0.f;

    if constexpr (SCALARX) {
        const float* xr[NPT];
#pragma unroll
        for (int i = 0; i < NPT; i++) {
            int n = nb0 + g * NPT + i;
            unsigned nu = (unsigned)__builtin_amdgcn_readfirstlane(n < n_nodes ? n : 0);
            xr[i] = x + (size_t)nu * FIN;
        }
#pragma unroll 8
        for (int k = 0; k < FIN; k++) {
            float w = W[k * HOUT + c];
#pragma unroll
            for (int i = 0; i < NPT; i++) acc[i] += w * xr[i][k];
        }
    } else {
        for (int k = 0; k < FIN; k++) {
            float w = W[k * HOUT + c];
#pragma unroll
            for (int i = 0; i < NPT; i++)
                acc[i] += w * xs[(g * NPT + i) * (FIN + 1) + k];
        }
    }

#pragma unroll
    for (int i = 0; i < NPT; i++) {
        int n = nb0 + g * NPT + i;
        bool ok = (n < n_nodes);
        float h = acc[i];
        if (ok) {
            if (BF16OUT)
                ((__hip_bfloat16*)hout)[(size_t)n * HOUT + c] = __float2bfloat16(h);
            else
                ((float*)hout)[(size_t)n * HOUT + c] = h;
        }
        float pa = h * aSv, pb = h * aDv;
#pragma unroll
        for (int off = 16; off >= 1; off >>= 1) {
            pa += __shfl_xor(pa, off, 32);
            pb += __shfl_xor(pb, off, 32);
        }
        if (ok && cc == 0) { asrc[n * H + head] = pa; adst[n * H + head] = pb; }
    }
}

// ---- CSR build: histogram -> 3-phase scan -> scatter ----
__global__ void kc_count(const int* __restrict__ ei1, int* __restrict__ cnt)
{
    int e = blockIdx.x * 256 + threadIdx.x;
    if (e >= E_EDGES) return;
    atomicAdd(&cnt[ei1[e]], 1);
}

__global__ __launch_bounds__(256) void kc_blocksum(const int* __restrict__ cnt,
                                                   int* __restrict__ bsum)
{
    __shared__ int sd[256];
    const int tid = threadIdx.x;
    int i = blockIdx.x * 256 + tid;
    int v = (i < N_NODES) ? cnt[i] : 0;
    sd[tid] = v;
    __syncthreads();
    for (int off = 128; off >= 1; off >>= 1) {
        if (tid < off) sd[tid] += sd[tid + off];
        __syncthreads();
    }
    if (tid == 0) bsum[blockIdx.x] = sd[0];
}

__global__ __launch_bounds__(256) void kc_scanbsum(const int* __restrict__ bsum,
                                                   int* __restrict__ bofs)
{
    __shared__ int sd[256];
    const int tid = threadIdx.x;
    int v = (tid < SCAN_NB) ? bsum[tid] : 0;
    sd[tid] = v;
    __syncthreads();
    for (int off = 1; off < 256; off <<= 1) {
        int u = (tid >= off) ? sd[tid - off] : 0;
        __syncthreads();
        sd[tid] += u;
        __syncthreads();
    }
    if (tid < SCAN_NB) bofs[tid] = sd[tid] - v;
}

__global__ __launch_bounds__(256) void kc_apply(const int* __restrict__ cnt,
                                                const int* __restrict__ bofs,
                                                int* __restrict__ rowptr,
                                                int* __restrict__ cur)
{
    __shared__ int sd[256];
    const int tid = threadIdx.x;
    int i = blockIdx.x * 256 + tid;
    int v = (i < N_NODES) ? cnt[i] : 0;
    sd[tid] = v;
    __syncthreads();
    for (int off = 1; off < 256; off <<= 1) {
        int u = (tid >= off) ? sd[tid - off] : 0;
        __syncthreads();
        sd[tid] += u;
        __syncthreads();
    }
    int excl = sd[tid] - v + bofs[blockIdx.x];
    if (i < N_NODES) { rowptr[i] = excl; cur[i] = excl; }
}

__global__ void kc_scatter(const int* __restrict__ ei0, const int* __restrict__ ei1,
                           int* __restrict__ cur, int* __restrict__ srcs)
{
    int e = blockIdx.x * 256 + threadIdx.x;
    if (e >= E_EDGES) return;
    int pos = atomicAdd(&cur[ei1[e]], 1);
    srcs[pos] = ei0[e];
}

// ---- fused aggregation: online segment-softmax + weighted sum + bias (+ELU) ----
template<int H, int C, bool DO_ELU, bool BF16H>
__global__ __launch_bounds__(256) void k_aggr(
    const float* __restrict__ asrc, const float* __restrict__ adst,
    const void* __restrict__ hbuf, const int* __restrict__ rowptr,
    const int* __restrict__ deg, const int* __restrict__ srcs,
    const float* __restrict__ b, float* __restrict__ outp)
{
    constexpr int HCL = H * C;
    constexpr int TPE = HCL / 2;
    constexpr int NPB = 256 / TPE;
    const int t = threadIdx.x % TPE;
    const int n = blockIdx.x * NPB + threadIdx.x / TPE;
    if (n >= N_NODES) return;
    const int c0 = 2 * t;
    const int head = c0 / C;
    const float adstv = adst[n * H + head];
    const unsigned* hbu = (const unsigned*)hbuf;
    const float* hbf = (const float*)hbuf;
    // init with self-loop
    float m = lrelu(asrc[n * H + head] + adstv);
    float ssum = 1.f;
    float a0, a1;
    if (BF16H) {
        unsigned u = hbu[(size_t)n * TPE + t];
        a0 = bflo(u); a1 = bfhi(u);
    } else {
        float2 hv = *(const float2*)(hbf + (size_t)n * HCL + c0);
        a0 = hv.x; a1 = hv.y;
    }
    const int base = rowptr[n];
    const int dg = deg[n];
    int i = 0;
    for (; i + 4 <= dg; i += 4) {
        int s0 = srcs[base + i + 0];
        int s1 = srcs[base + i + 1];
        int s2 = srcs[base + i + 2];
        int s3 = srcs[base + i + 3];
        float sc[4];
        sc[0] = lrelu(asrc[s0 * H + head] + adstv);
        sc[1] = lrelu(asrc[s1 * H + head] + adstv);
        sc[2] = lrelu(asrc[s2 * H + head] + adstv);
        sc[3] = lrelu(asrc[s3 * H + head] + adstv);
        float hx[4], hy[4];
        if (BF16H) {
            unsigned u0 = hbu[(size_t)s0 * TPE + t];
            unsigned u1 = hbu[(size_t)s1 * TPE + t];
            unsigned u2 = hbu[(size_t)s2 * TPE + t];
            unsigned u3 = hbu[(size_t)s3 * TPE + t];
            hx[0] = bflo(u0); hy[0] = bfhi(u0);
            hx[1] = bflo(u1); hy[1] = bfhi(u1);
            hx[2] = bflo(u2); hy[2] = bfhi(u2);
            hx[3] = bflo(u3); hy[3] = bfhi(u3);
        } else {
            float2 h0 = *(const float2*)(hbf + (size_t)s0 * HCL + c0);
            float2 h1 = *(const float2*)(hbf + (size_t)s1 * HCL + c0);
            float2 h2 = *(const float2*)(hbf + (size_t)s2 * HCL + c0);
            float2 h3 = *(const float2*)(hbf + (size_t)s3 * HCL + c0);
            hx[0] = h0.x; hy[0] = h0.y;
            hx[1] = h1.x; hy[1] = h1.y;
            hx[2] = h2.x; hy[2] = h2.y;
            hx[3] = h3.x; hy[3] = h3.y;
        }
#pragma unroll
        for (int u = 0; u < 4; u++) {
            float scv = sc[u];
            float ex;
            if (scv > m) {
                float r = __expf(m - scv);
                ssum *= r; a0 *= r; a1 *= r;
                m = scv;
                ex = 1.f;
            } else {
                ex = __expf(scv - m);
            }
            ssum += ex;
            a0 += ex * hx[u];
            a1 += ex * hy[u];
        }
    }
    for (; i < dg; i++) {
        int s = srcs[base + i];
        float sc = lrelu(asrc[s * H + head] + adstv);
        float hxv, hyv;
        if (BF16H) {
            unsigned u = hbu[(size_t)s * TPE + t];
            hxv = bflo(u); hyv = bfhi(u);
        } else {
            float2 hs = *(const float2*)(hbf + (size_t)s * HCL + c0);
            hxv = hs.x; hyv = hs.y;
        }
        float ex;
        if (sc > m) {
            float r = __expf(m - sc);
            ssum *= r; a0 *= r; a1 *= r;
            m = sc;
            ex = 1.f;
        } else {
            ex = __expf(sc - m);
        }
        ssum += ex;
        a0 += ex * hxv;
        a1 += ex * hyv;
    }
    float inv = 1.f / (ssum + 1e-16f);
    float v0 = a0 * inv + b[c0];
    float v1 = a1 * inv + b[c0 + 1];
    if (DO_ELU) {
        v0 = v0 > 0.f ? v0 : __expf(v0) - 1.f;
        v1 = v1 > 0.f ? v1 : __expf(v1) - 1.f;
    }
    *(float2*)(outp + (size_t)n * HCL + c0) = make_float2(v0, v1);
}

// ---- K5a: node-level precompute for MLP layer 1 (bf16 output) ----
__global__ __launch_bounds__(256) void k5a_precomp(
    const float* __restrict__ h3, const float* __restrict__ Wm1,
    __hip_bfloat16* __restrict__ Pb)
{
    __shared__ __align__(16) float w[64 * 32];      // rows 0..63 of Wm1
    __shared__ __align__(16) float hsh[16][33];
    const int tid = threadIdx.x;
    for (int i = tid; i < 64 * 32; i += 256) w[i] = Wm1[i];
    const int nb0 = blockIdx.x * 16;
    for (int idx = tid; idx < 16 * 32; idx += 256) {
        int node = idx / 32, k = idx % 32;
        int gn = nb0 + node;
        hsh[node][k] = (gn < N_NODES) ? h3[gn * 32 + k] : 0.f;
    }
    __syncthreads();
    const int c = tid % 64;           // output channel 0..63
    const int part = c / 32;          // 0 -> W1a, 1 -> W1b
    const int j = c % 32;
    for (int ln = tid / 64; ln < 16; ln += 4) {
        int gn = nb0 + ln;
        if (gn >= N_NODES) break;
        float sum = 0.f;
#pragma unroll
        for (int k = 0; k < 32; k++)
            sum += hsh[ln][k] * w[(part * 32 + k) * 32 + j];
        Pb[(size_t)gn * 64 + c] = __float2bfloat16(sum);
    }
}

// ---- K5b: per-edge MLP, NO LDS: all weights are wave-uniform -> scalar loads ----
__global__ __launch_bounds__(256) void k5b_mlp(
                       const int* __restrict__ ei0, const int* __restrict__ ei1,
                       const __hip_bfloat16* __restrict__ Pb, const float* __restrict__ ea,
                       const float* __restrict__ Wm1, const float* __restrict__ bm1,
                       const float* __restrict__ Wm2, const float* __restrict__ bm2,
                       const float* __restrict__ Wm3, const float* __restrict__ bm3,
                       float* __restrict__ out)
{
    const int e = blockIdx.x * 256 + threadIdx.x;
    if (e >= E_EDGES) return;
    const int s = ei0[e], d = ei1[e];

    float z1[32];
#pragma unroll
    for (int j = 0; j < 32; j++) z1[j] = bm1[j];

    // edge_attr contribution (8x32) — weights uniform from global (s_load)
    const f4v* eav = (const f4v*)(ea + (size_t)e * 8);
#pragma unroll
    for (int kq = 0; kq < 2; kq++) {
        f4v v = __builtin_nontemporal_load(&eav[kq]);
        const float* wrow = Wm1 + (64 + kq * 4) * 32;
#pragma unroll
        for (int j = 0; j < 32; j++) z1[j] += v.x * wrow[0 * 32 + j];
#pragma unroll
        for (int j = 0; j < 32; j++) z1[j] += v.y * wrow[1 * 32 + j];
#pragma unroll
        for (int j = 0; j < 32; j++) z1[j] += v.z * wrow[2 * 32 + j];
#pragma unroll
        for (int j = 0; j < 32; j++) z1[j] += v.w * wrow[3 * 32 + j];
    }
    // node contributions: one 64B line per side (bf16), per-lane gathers
    const uint4* ps4 = (const uint4*)(Pb + (size_t)s * 64);
    const uint4* pd4 = (const uint4*)(Pb + (size_t)d * 64 + 32);
#pragma unroll
    for (int q = 0; q < 4; q++) {
        uint4 a = ps4[q];
        uint4 b = pd4[q];
        z1[8 * q + 0] += bflo(a.x) + bflo(b.x);
        z1[8 * q + 1] += bfhi(a.x) + bfhi(b.x);
        z1[8 * q + 2] += bflo(a.y) + bflo(b.y);
        z1[8 * q + 3] += bfhi(a.y) + bfhi(b.y);
        z1[8 * q + 4] += bflo(a.z) + bflo(b.z);
        z1[8 * q + 5] += bfhi(a.z) + bfhi(b.z);
        z1[8 * q + 6] += bflo(a.w) + bflo(b.w);
        z1[8 * q + 7] += bfhi(a.w) + bfhi(b.w);
    }
#pragma unroll
    for (int j = 0; j < 32; j++) z1[j] = z1[j] > 0.f ? z1[j] : 0.f;

    // z2: k-outer; w2 rows uniform from global (s_load), FMA takes SGPR operand
    float acc2[32];
#pragma unroll
    for (int j = 0; j < 32; j++) acc2[j] = bm2[j];
#pragma unroll
    for (int k = 0; k < 32; k++) {
        float zk = z1[k];
        const float* w2r = Wm2 + k * 32;
#pragma unroll
        for (int j = 0; j < 32; j++) acc2[j] += zk * w2r[j];
    }
    float z3 = bm3[0];
#pragma unroll
    for (int j = 0; j < 32; j++) z3 += (acc2[j] > 0.f ? acc2[j] : 0.f) * Wm3[j];

    float r = (z3 > 20.f) ? z3 : log1pf(__expf(z3));
    __builtin_nontemporal_store(r, &out[e]);
}

extern "C" void kernel_launch(void* const* d_in, const int* in_sizes, int n_in,
                              void* d_out, int out_size, void* d_ws, size_t ws_size,
                              hipStream_t stream)
{
    const float* x   = (const float*)d_in[0];
    const int*   ei  = (const int*)d_in[1];
    const int*   ei0 = ei;
    const int*   ei1 = ei + E_EDGES;
    const float* ea  = (const float*)d_in[2];
    const float* W1  = (const float*)d_in[3];
    const float* aS1 = (const float*)d_in[4];
    const float* aD1 = (const float*)d_in[5];
    const float* b1  = (const float*)d_in[6];
    const float* W2  = (const float*)d_in[7];
    const float* aS2 = (const float*)d_in[8];
    const float* aD2 = (const float*)d_in[9];
    const float* b2  = (const float*)d_in[10];
    const float* W3  = (const float*)d_in[11];
    const float* aS3 = (const float*)d_in[12];
    const float* aD3 = (const float*)d_in[13];
    const float* b3  = (const float*)d_in[14];
    const float* Wm1 = (const float*)d_in[15];
    const float* bm1 = (const float*)d_in[16];
    const float* Wm2 = (const float*)d_in[17];
    const float* bm2 = (const float*)d_in[18];
    const float* Wm3 = (const float*)d_in[19];
    const float* bm3 = (const float*)d_in[20];

    float* ws = (float*)d_ws;
    float* bufA = ws;                                    // h (bf16 L1/L2, f32 L3) / later Pb
    float* bufB = bufA + (size_t)N_NODES * HC;           // [N,128] layer output (f32)
    float* asrc = bufB + (size_t)N_NODES * HC;           // [N,4]
    float* adst = asrc + (size_t)N_NODES * HEADS;        // [N,4]
    int* cnt    = (int*)(adst + (size_t)N_NODES * HEADS);// [N] in-degree (no self-loop)
    int* rowptr = cnt + N_NODES;                         // [N]
    int* cur    = rowptr + N_NODES;                      // [N]
    int* srcs   = cur + N_NODES;                         // [E]
    int* bsum   = srcs + E_EDGES;                        // [SCAN_NB]
    int* bofs   = bsum + 256;                            // [SCAN_NB]

    float* out = (float*)d_out;

    // ---------------- CSR build (once; shared by all 3 layers) ----------------
    hipMemsetAsync(cnt, 0, (size_t)N_NODES * sizeof(int), stream);
    kc_count<<<(E_EDGES + 255) / 256, 256, 0, stream>>>(ei1, cnt);
    kc_blocksum<<<SCAN_NB, 256, 0, stream>>>(cnt, bsum);
    kc_scanbsum<<<1, 256, 0, stream>>>(bsum, bofs);
    kc_apply<<<SCAN_NB, 256, 0, stream>>>(cnt, bofs, rowptr, cur);
    kc_scatter<<<(E_EDGES + 255) / 256, 256, 0, stream>>>(ei0, ei1, cur, srcs);

    // ---------------- Layer 1: x[N,16] -> bufB[N,128] (ELU), bf16 h ----------------
    k1_gemm_alpha<NFEAT, HC, HEADS, true><<<(N_NODES + 7) / 8, 256, 0, stream>>>(
        x, W1, aS1, aD1, bufA, asrc, adst, N_NODES);
    k_aggr<HEADS, HID, true, true><<<(N_NODES + 3) / 4, 256, 0, stream>>>(
        asrc, adst, bufA, rowptr, cnt, srcs, b1, bufB);

    // ---------------- Layer 2: bufB[N,128] -> bufB[N,128] (ELU), bf16 h ----------------
    k1_gemm_alpha<HC, HC, HEADS, true><<<(N_NODES + 7) / 8, 256, 0, stream>>>(
        bufB, W2, aS2, aD2, bufA, asrc, adst, N_NODES);
    k_aggr<HEADS, HID, true, true><<<(N_NODES + 3) / 4, 256, 0, stream>>>(
        asrc, adst, bufA, rowptr, cnt, srcs, b2, bufB);

    // ---------------- Layer 3: bufB[N,128] -> bufB[N,32] (no act, H=1), fp32 ----------------
    k1_gemm_alpha<HC, HID, 1, false><<<(N_NODES + 31) / 32, 256, 0, stream>>>(
        bufB, W3, aS3, aD3, bufA, asrc, adst, N_NODES);
    k_aggr<1, HID, false, false><<<(N_NODES + 15) / 16, 256, 0, stream>>>(
        asrc, adst, bufA, rowptr, cnt, srcs, b3, bufB);

    // ---------------- Edge MLP: node precompute (bf16), then per-edge ----------------
    __hip_bfloat16* Pb = (__hip_bfloat16*)bufA;   // bufA free after layer 3
    k5a_precomp<<<(N_NODES + 15) / 16, 256, 0, stream>>>(bufB, Wm1, Pb);
    k5b_mlp<<<(E_EDGES + 255) / 256, 256, 0, stream>>>(
        ei0, ei1, Pb, ea, Wm1, bm1, Wm2, bm2, Wm3, bm3, out);
}

// Round 13
// 359.057 us; speedup vs baseline: 5.7102x; 1.0941x over previous
//
#include <hip/hip_runtime.h>
#include <hip/hip_bf16.h>
#include <math.h>

#define N_NODES 50000
#define E_EDGES 800000
#define NFEAT 16
#define EFEAT 8
#define HID 32
#define HEADS 4
#define HC 128
#define SCAN_NB ((N_NODES + 255) / 256)   // 196

typedef float f4v __attribute__((ext_vector_type(4)));

__device__ __forceinline__ float lrelu(float v) { return v > 0.f ? v : 0.2f * v; }
__device__ __forceinline__ float bflo(unsigned u) { return __uint_as_float(u << 16); }
__device__ __forceinline__ float bfhi(unsigned u) { return __uint_as_float(u & 0xffff0000u); }
__device__ __forceinline__ f4v relu4(f4v v) {
    f4v r;
    r.x = v.x > 0.f ? v.x : 0.f;
    r.y = v.y > 0.f ? v.y : 0.f;
    r.z = v.z > 0.f ? v.z : 0.f;
    r.w = v.w > 0.f ? v.w : 0.f;
    return r;
}

// ---- K1: h = x @ W ; alpha_src/dst = einsum(h, aS/aD) per head ----
// (unchanged from R12 — proven)
template<int FIN, int HOUT, int H, bool BF16OUT>
__global__ void k1_gemm_alpha(const float* __restrict__ x, const float* __restrict__ W,
                              const float* __restrict__ aS, const float* __restrict__ aD,
                              void* __restrict__ hout, float* __restrict__ asrc,
                              float* __restrict__ adst, int n_nodes)
{
    constexpr int GROUPS = 256 / HOUT;
    constexpr int NPT = 4;
    constexpr int NPB = GROUPS * NPT;
    constexpr bool SCALARX = (HOUT >= 64);
    __shared__ float xs[SCALARX ? 1 : NPB * (FIN + 1)];
    const int tid = threadIdx.x;
    const int nb0 = blockIdx.x * NPB;
    const int c = tid % HOUT;
    const int g = tid / HOUT;

    if constexpr (!SCALARX) {
        for (int idx = tid; idx < NPB * FIN; idx += 256) {
            int node = idx / FIN, k = idx % FIN;
            int gn = nb0 + node;
            xs[node * (FIN + 1) + k] = (gn < n_nodes) ? x[(size_t)gn * FIN + k] : 0.f;
        }
        __syncthreads();
    }

    const int head = c / HID;
    const int cc = c % HID;
    const float aSv = aS[head * HID + cc];
    const float aDv = aD[head * HID + cc];
    float acc[NPT];
#pragma unroll
    for (int i = 0; i < NPT; i++) acc[i] = 0.f;

    if constexpr (SCALARX) {
        const float* xr[NPT];
#pragma unroll
        for (int i = 0; i < NPT; i++) {
            int n = nb0 + g * NPT + i;
            unsigned nu = (unsigned)__builtin_amdgcn_readfirstlane(n < n_nodes ? n : 0);
            xr[i] = x + (size_t)nu * FIN;
        }
#pragma unroll 8
        for (int k = 0; k < FIN; k++) {
            float w = W[k * HOUT + c];
#pragma unroll
            for (int i = 0; i < NPT; i++) acc[i] += w * xr[i][k];
        }
    } else {
        for (int k = 0; k < FIN; k++) {
            float w = W[k * HOUT + c];
#pragma unroll
            for (int i = 0; i < NPT; i++)
                acc[i] += w * xs[(g * NPT + i) * (FIN + 1) + k];
        }
    }

#pragma unroll
    for (int i = 0; i < NPT; i++) {
        int n = nb0 + g * NPT + i;
        bool ok = (n < n_nodes);
        float h = acc[i];
        if (ok) {
            if (BF16OUT)
                ((__hip_bfloat16*)hout)[(size_t)n * HOUT + c] = __float2bfloat16(h);
            else
                ((float*)hout)[(size_t)n * HOUT + c] = h;
        }
        float pa = h * aSv, pb = h * aDv;
#pragma unroll
        for (int off = 16; off >= 1; off >>= 1) {
            pa += __shfl_xor(pa, off, 32);
            pb += __shfl_xor(pb, off, 32);
        }
        if (ok && cc == 0) { asrc[n * H + head] = pa; adst[n * H + head] = pb; }
    }
}

// ---- CSR build: histogram -> 3-phase scan -> scatter ----
__global__ void kc_count(const int* __restrict__ ei1, int* __restrict__ cnt)
{
    int e = blockIdx.x * 256 + threadIdx.x;
    if (e >= E_EDGES) return;
    atomicAdd(&cnt[ei1[e]], 1);
}

__global__ __launch_bounds__(256) void kc_blocksum(const int* __restrict__ cnt,
                                                   int* __restrict__ bsum)
{
    __shared__ int sd[256];
    const int tid = threadIdx.x;
    int i = blockIdx.x * 256 + tid;
    int v = (i < N_NODES) ? cnt[i] : 0;
    sd[tid] = v;
    __syncthreads();
    for (int off = 128; off >= 1; off >>= 1) {
        if (tid < off) sd[tid] += sd[tid + off];
        __syncthreads();
    }
    if (tid == 0) bsum[blockIdx.x] = sd[0];
}

__global__ __launch_bounds__(256) void kc_scanbsum(const int* __restrict__ bsum,
                                                   int* __restrict__ bofs)
{
    __shared__ int sd[256];
    const int tid = threadIdx.x;
    int v = (tid < SCAN_NB) ? bsum[tid] : 0;
    sd[tid] = v;
    __syncthreads();
    for (int off = 1; off < 256; off <<= 1) {
        int u = (tid >= off) ? sd[tid - off] : 0;
        __syncthreads();
        sd[tid] += u;
        __syncthreads();
    }
    if (tid < SCAN_NB) bofs[tid] = sd[tid] - v;
}

__global__ __launch_bounds__(256) void kc_apply(const int* __restrict__ cnt,
                                                const int* __restrict__ bofs,
                                                int* __restrict__ rowptr,
                                                int* __restrict__ cur)
{
    __shared__ int sd[256];
    const int tid = threadIdx.x;
    int i = blockIdx.x * 256 + tid;
    int v = (i < N_NODES) ? cnt[i] : 0;
    sd[tid] = v;
    __syncthreads();
    for (int off = 1; off < 256; off <<= 1) {
        int u = (tid >= off) ? sd[tid - off] : 0;
        __syncthreads();
        sd[tid] += u;
        __syncthreads();
    }
    int excl = sd[tid] - v + bofs[blockIdx.x];
    if (i < N_NODES) { rowptr[i] = excl; cur[i] = excl; }
}

__global__ void kc_scatter(const int* __restrict__ ei0, const int* __restrict__ ei1,
                           int* __restrict__ cur, int* __restrict__ srcs)
{
    int e = blockIdx.x * 256 + threadIdx.x;
    if (e >= E_EDGES) return;
    int pos = atomicAdd(&cur[ei1[e]], 1);
    srcs[pos] = ei0[e];
}

// ---- fused aggregation (unchanged from R12) ----
template<int H, int C, bool DO_ELU, bool BF16H>
__global__ __launch_bounds__(256) void k_aggr(
    const float* __restrict__ asrc, const float* __restrict__ adst,
    const void* __restrict__ hbuf, const int* __restrict__ rowptr,
    const int* __restrict__ deg, const int* __restrict__ srcs,
    const float* __restrict__ b, float* __restrict__ outp)
{
    constexpr int HCL = H * C;
    constexpr int TPE = HCL / 2;
    constexpr int NPB = 256 / TPE;
    const int t = threadIdx.x % TPE;
    const int n = blockIdx.x * NPB + threadIdx.x / TPE;
    if (n >= N_NODES) return;
    const int c0 = 2 * t;
    const int head = c0 / C;
    const float adstv = adst[n * H + head];
    const unsigned* hbu = (const unsigned*)hbuf;
    const float* hbf = (const float*)hbuf;
    float m = lrelu(asrc[n * H + head] + adstv);
    float ssum = 1.f;
    float a0, a1;
    if (BF16H) {
        unsigned u = hbu[(size_t)n * TPE + t];
        a0 = bflo(u); a1 = bfhi(u);
    } else {
        float2 hv = *(const float2*)(hbf + (size_t)n * HCL + c0);
        a0 = hv.x; a1 = hv.y;
    }
    const int base = rowptr[n];
    const int dg = deg[n];
    int i = 0;
    for (; i + 4 <= dg; i += 4) {
        int s0 = srcs[base + i + 0];
        int s1 = srcs[base + i + 1];
        int s2 = srcs[base + i + 2];
        int s3 = srcs[base + i + 3];
        float sc[4];
        sc[0] = lrelu(asrc[s0 * H + head] + adstv);
        sc[1] = lrelu(asrc[s1 * H + head] + adstv);
        sc[2] = lrelu(asrc[s2 * H + head] + adstv);
        sc[3] = lrelu(asrc[s3 * H + head] + adstv);
        float hx[4], hy[4];
        if (BF16H) {
            unsigned u0 = hbu[(size_t)s0 * TPE + t];
            unsigned u1 = hbu[(size_t)s1 * TPE + t];
            unsigned u2 = hbu[(size_t)s2 * TPE + t];
            unsigned u3 = hbu[(size_t)s3 * TPE + t];
            hx[0] = bflo(u0); hy[0] = bfhi(u0);
            hx[1] = bflo(u1); hy[1] = bfhi(u1);
            hx[2] = bflo(u2); hy[2] = bfhi(u2);
            hx[3] = bflo(u3); hy[3] = bfhi(u3);
        } else {
            float2 h0 = *(const float2*)(hbf + (size_t)s0 * HCL + c0);
            float2 h1 = *(const float2*)(hbf + (size_t)s1 * HCL + c0);
            float2 h2 = *(const float2*)(hbf + (size_t)s2 * HCL + c0);
            float2 h3 = *(const float2*)(hbf + (size_t)s3 * HCL + c0);
            hx[0] = h0.x; hy[0] = h0.y;
            hx[1] = h1.x; hy[1] = h1.y;
            hx[2] = h2.x; hy[2] = h2.y;
            hx[3] = h3.x; hy[3] = h3.y;
        }
#pragma unroll
        for (int u = 0; u < 4; u++) {
            float scv = sc[u];
            float ex;
            if (scv > m) {
                float r = __expf(m - scv);
                ssum *= r; a0 *= r; a1 *= r;
                m = scv;
                ex = 1.f;
            } else {
                ex = __expf(scv - m);
            }
            ssum += ex;
            a0 += ex * hx[u];
            a1 += ex * hy[u];
        }
    }
    for (; i < dg; i++) {
        int s = srcs[base + i];
        float sc = lrelu(asrc[s * H + head] + adstv);
        float hxv, hyv;
        if (BF16H) {
            unsigned u = hbu[(size_t)s * TPE + t];
            hxv = bflo(u); hyv = bfhi(u);
        } else {
            float2 hs = *(const float2*)(hbf + (size_t)s * HCL + c0);
            hxv = hs.x; hyv = hs.y;
        }
        float ex;
        if (sc > m) {
            float r = __expf(m - sc);
            ssum *= r; a0 *= r; a1 *= r;
            m = sc;
            ex = 1.f;
        } else {
            ex = __expf(sc - m);
        }
        ssum += ex;
        a0 += ex * hxv;
        a1 += ex * hyv;
    }
    float inv = 1.f / (ssum + 1e-16f);
    float v0 = a0 * inv + b[c0];
    float v1 = a1 * inv + b[c0 + 1];
    if (DO_ELU) {
        v0 = v0 > 0.f ? v0 : __expf(v0) - 1.f;
        v1 = v1 > 0.f ? v1 : __expf(v1) - 1.f;
    }
    *(float2*)(outp + (size_t)n * HCL + c0) = make_float2(v0, v1);
}

// ---- K5a: node-level precompute for MLP layer 1 (bf16 output, unchanged) ----
__global__ __launch_bounds__(256) void k5a_precomp(
    const float* __restrict__ h3, const float* __restrict__ Wm1,
    __hip_bfloat16* __restrict__ Pb)
{
    __shared__ __align__(16) float w[64 * 32];
    __shared__ __align__(16) float hsh[16][33];
    const int tid = threadIdx.x;
    for (int i = tid; i < 64 * 32; i += 256) w[i] = Wm1[i];
    const int nb0 = blockIdx.x * 16;
    for (int idx = tid; idx < 16 * 32; idx += 256) {
        int node = idx / 32, k = idx % 32;
        int gn = nb0 + node;
        hsh[node][k] = (gn < N_NODES) ? h3[gn * 32 + k] : 0.f;
    }
    __syncthreads();
    const int c = tid % 64;
    const int part = c / 32;
    const int j = c % 32;
    for (int ln = tid / 64; ln < 16; ln += 4) {
        int gn = nb0 + ln;
        if (gn >= N_NODES) break;
        float sum = 0.f;
#pragma unroll
        for (int k = 0; k < 32; k++)
            sum += hsh[ln][k] * w[(part * 32 + k) * 32 + j];
        Pb[(size_t)gn * 64 + c] = __float2bfloat16(sum);
    }
}

// ---- K5b: per-edge MLP; weights scalar-loaded, arithmetic in f4v form so
// the compiler emits v_pk_fma_f32 (2 MACs/instr). Same summation order. ----
__global__ __launch_bounds__(256, 4) void k5b_mlp(
                       const int* __restrict__ ei0, const int* __restrict__ ei1,
                       const __hip_bfloat16* __restrict__ Pb, const float* __restrict__ ea,
                       const float* __restrict__ Wm1, const float* __restrict__ bm1,
                       const float* __restrict__ Wm2, const float* __restrict__ bm2,
                       const float* __restrict__ Wm3, const float* __restrict__ bm3,
                       float* __restrict__ out)
{
    const int e = blockIdx.x * 256 + threadIdx.x;
    if (e >= E_EDGES) return;
    const int s = ei0[e], d = ei1[e];

    const f4v* bm1v = (const f4v*)bm1;
    f4v z1v[8];
#pragma unroll
    for (int q = 0; q < 8; q++) z1v[q] = bm1v[q];

    // edge_attr contribution (8x32); weight rows wave-uniform -> scalar loads
    const f4v* eav = (const f4v*)(ea + (size_t)e * 8);
#pragma unroll
    for (int kq = 0; kq < 2; kq++) {
        f4v v = eav[kq];
#pragma unroll
        for (int r = 0; r < 4; r++) {
            float vr = (r == 0) ? v.x : (r == 1) ? v.y : (r == 2) ? v.z : v.w;
            const f4v* w4 = (const f4v*)(Wm1 + (64 + kq * 4 + r) * 32);
#pragma unroll
            for (int q = 0; q < 8; q++) z1v[q] += w4[q] * vr;
        }
    }
    // node contributions: one 64B bf16 line per side
    const uint4* ps4 = (const uint4*)(Pb + (size_t)s * 64);
    const uint4* pd4 = (const uint4*)(Pb + (size_t)d * 64 + 32);
#pragma unroll
    for (int q = 0; q < 4; q++) {
        uint4 a = ps4[q];
        uint4 b = pd4[q];
        f4v pa0 = {bflo(a.x), bfhi(a.x), bflo(a.y), bfhi(a.y)};
        f4v pa1 = {bflo(a.z), bfhi(a.z), bflo(a.w), bfhi(a.w)};
        f4v pb0 = {bflo(b.x), bfhi(b.x), bflo(b.y), bfhi(b.y)};
        f4v pb1 = {bflo(b.z), bfhi(b.z), bflo(b.w), bfhi(b.w)};
        z1v[2 * q + 0] += pa0 + pb0;
        z1v[2 * q + 1] += pa1 + pb1;
    }
#pragma unroll
    for (int q = 0; q < 8; q++) z1v[q] = relu4(z1v[q]);

    // z2: k-outer; acc2v[q] += w4*zk -> packed FMAs
    const f4v* bm2v = (const f4v*)bm2;
    f4v acc2v[8];
#pragma unroll
    for (int q = 0; q < 8; q++) acc2v[q] = bm2v[q];
#pragma unroll
    for (int k = 0; k < 32; k++) {
        float zk = z1v[k >> 2][k & 3];
        const f4v* w4 = (const f4v*)(Wm2 + k * 32);
#pragma unroll
        for (int q = 0; q < 8; q++) acc2v[q] += w4[q] * zk;
    }
    float z3 = bm3[0];
#pragma unroll
    for (int q = 0; q < 8; q++) {
        const float* w3q = Wm3 + 4 * q;
        float c0 = acc2v[q].x, c1 = acc2v[q].y, c2 = acc2v[q].z, c3 = acc2v[q].w;
        z3 += (c0 > 0.f ? c0 : 0.f) * w3q[0];
        z3 += (c1 > 0.f ? c1 : 0.f) * w3q[1];
        z3 += (c2 > 0.f ? c2 : 0.f) * w3q[2];
        z3 += (c3 > 0.f ? c3 : 0.f) * w3q[3];
    }

    float r = (z3 > 20.f) ? z3 : log1pf(__expf(z3));
    __builtin_nontemporal_store(r, &out[e]);
}

extern "C" void kernel_launch(void* const* d_in, const int* in_sizes, int n_in,
                              void* d_out, int out_size, void* d_ws, size_t ws_size,
                              hipStream_t stream)
{
    const float* x   = (const float*)d_in[0];
    const int*   ei  = (const int*)d_in[1];
    const int*   ei0 = ei;
    const int*   ei1 = ei + E_EDGES;
    const float* ea  = (const float*)d_in[2];
    const float* W1  = (const float*)d_in[3];
    const float* aS1 = (const float*)d_in[4];
    const float* aD1 = (const float*)d_in[5];
    const float* b1  = (const float*)d_in[6];
    const float* W2  = (const float*)d_in[7];
    const float* aS2 = (const float*)d_in[8];
    const float* aD2 = (const float*)d_in[9];
    const float* b2  = (const float*)d_in[10];
    const float* W3  = (const float*)d_in[11];
    const float* aS3 = (const float*)d_in[12];
    const float* aD3 = (const float*)d_in[13];
    const float* b3  = (const float*)d_in[14];
    const float* Wm1 = (const float*)d_in[15];
    const float* bm1 = (const float*)d_in[16];
    const float* Wm2 = (const float*)d_in[17];
    const float* bm2 = (const float*)d_in[18];
    const float* Wm3 = (const float*)d_in[19];
    const float* bm3 = (const float*)d_in[20];

    float* ws = (float*)d_ws;
    float* bufA = ws;                                    // h (bf16 L1/L2, f32 L3) / later Pb
    float* bufB = bufA + (size_t)N_NODES * HC;           // [N,128] layer output (f32)
    float* asrc = bufB + (size_t)N_NODES * HC;           // [N,4]
    float* adst = asrc + (size_t)N_NODES * HEADS;        // [N,4]
    int* cnt    = (int*)(adst + (size_t)N_NODES * HEADS);// [N]
    int* rowptr = cnt + N_NODES;                         // [N]
    int* cur    = rowptr + N_NODES;                      // [N]
    int* srcs   = cur + N_NODES;                         // [E]
    int* bsum   = srcs + E_EDGES;                        // [SCAN_NB]
    int* bofs   = bsum + 256;                            // [SCAN_NB]

    float* out = (float*)d_out;

    // ---------------- CSR build (once; shared by all 3 layers) ----------------
    hipMemsetAsync(cnt, 0, (size_t)N_NODES * sizeof(int), stream);
    kc_count<<<(E_EDGES + 255) / 256, 256, 0, stream>>>(ei1, cnt);
    kc_blocksum<<<SCAN_NB, 256, 0, stream>>>(cnt, bsum);
    kc_scanbsum<<<1, 256, 0, stream>>>(bsum, bofs);
    kc_apply<<<SCAN_NB, 256, 0, stream>>>(cnt, bofs, rowptr, cur);
    kc_scatter<<<(E_EDGES + 255) / 256, 256, 0, stream>>>(ei0, ei1, cur, srcs);

    // ---------------- Layer 1: x[N,16] -> bufB[N,128] (ELU), bf16 h ----------------
    k1_gemm_alpha<NFEAT, HC, HEADS, true><<<(N_NODES + 7) / 8, 256, 0, stream>>>(
        x, W1, aS1, aD1, bufA, asrc, adst, N_NODES);
    k_aggr<HEADS, HID, true, true><<<(N_NODES + 3) / 4, 256, 0, stream>>>(
        asrc, adst, bufA, rowptr, cnt, srcs, b1, bufB);

    // ---------------- Layer 2: bufB[N,128] -> bufB[N,128] (ELU), bf16 h ----------------
    k1_gemm_alpha<HC, HC, HEADS, true><<<(N_NODES + 7) / 8, 256, 0, stream>>>(
        bufB, W2, aS2, aD2, bufA, asrc, adst, N_NODES);
    k_aggr<HEADS, HID, true, true><<<(N_NODES + 3) / 4, 256, 0, stream>>>(
        asrc, adst, bufA, rowptr, cnt, srcs, b2, bufB);

    // ---------------- Layer 3: bufB[N,128] -> bufB[N,32] (no act, H=1), fp32 ----------------
    k1_gemm_alpha<HC, HID, 1, false><<<(N_NODES + 31) / 32, 256, 0, stream>>>(
        bufB, W3, aS3, aD3, bufA, asrc, adst, N_NODES);
    k_aggr<1, HID, false, false><<<(N_NODES + 15) / 16, 256, 0, stream>>>(
        asrc, adst, bufA, rowptr, cnt, srcs, b3, bufB);

    // ---------------- Edge MLP: node precompute (bf16), then per-edge ----------------
    __hip_bfloat16* Pb = (__hip_bfloat16*)bufA;   // bufA free after layer 3
    k5a_precomp<<<(N_NODES + 15) / 16, 256, 0, stream>>>(bufB, Wm1, Pb);
    k5b_mlp<<<(E_EDGES + 255) / 256, 256, 0, stream>>>(
        ei0, ei1, Pb, ea, Wm1, bm1, Wm2, bm2, Wm3, bm3, out);
}

// Round 14
// 315.356 us; speedup vs baseline: 6.5015x; 1.1386x over previous
//
#include <hip/hip_runtime.h>
#include <hip/hip_bf16.h>
#include <math.h>

#define N_NODES 50000
#define E_EDGES 800000
#define NFEAT 16
#define EFEAT 8
#define HID 32
#define HEADS 4
#define HC 128
#define SCAN_NB ((N_NODES + 255) / 256)   // 196

typedef float f4v __attribute__((ext_vector_type(4)));

__device__ __forceinline__ float lrelu(float v) { return v > 0.f ? v : 0.2f * v; }
__device__ __forceinline__ float bflo(unsigned u) { return __uint_as_float(u << 16); }
__device__ __forceinline__ float bfhi(unsigned u) { return __uint_as_float(u & 0xffff0000u); }
__device__ __forceinline__ f4v relu4(f4v v) {
    f4v r;
    r.x = v.x > 0.f ? v.x : 0.f;
    r.y = v.y > 0.f ? v.y : 0.f;
    r.z = v.z > 0.f ? v.z : 0.f;
    r.w = v.w > 0.f ? v.w : 0.f;
    return r;
}

// ---- K1: h = x @ W ; alpha_src/dst = einsum(h, aS/aD) per head (unchanged) ----
template<int FIN, int HOUT, int H, bool BF16OUT>
__global__ void k1_gemm_alpha(const float* __restrict__ x, const float* __restrict__ W,
                              const float* __restrict__ aS, const float* __restrict__ aD,
                              void* __restrict__ hout, float* __restrict__ asrc,
                              float* __restrict__ adst, int n_nodes)
{
    constexpr int GROUPS = 256 / HOUT;
    constexpr int NPT = 4;
    constexpr int NPB = GROUPS * NPT;
    constexpr bool SCALARX = (HOUT >= 64);
    __shared__ float xs[SCALARX ? 1 : NPB * (FIN + 1)];
    const int tid = threadIdx.x;
    const int nb0 = blockIdx.x * NPB;
    const int c = tid % HOUT;
    const int g = tid / HOUT;

    if constexpr (!SCALARX) {
        for (int idx = tid; idx < NPB * FIN; idx += 256) {
            int node = idx / FIN, k = idx % FIN;
            int gn = nb0 + node;
            xs[node * (FIN + 1) + k] = (gn < n_nodes) ? x[(size_t)gn * FIN + k] : 0.f;
        }
        __syncthreads();
    }

    const int head = c / HID;
    const int cc = c % HID;
    const float aSv = aS[head * HID + cc];
    const float aDv = aD[head * HID + cc];
    float acc[NPT];
#pragma unroll
    for (int i = 0; i < NPT; i++) acc[i] = 0.f;

    if constexpr (SCALARX) {
        const float* xr[NPT];
#pragma unroll
        for (int i = 0; i < NPT; i++) {
            int n = nb0 + g * NPT + i;
            unsigned nu = (unsigned)__builtin_amdgcn_readfirstlane(n < n_nodes ? n : 0);
            xr[i] = x + (size_t)nu * FIN;
        }
#pragma unroll 8
        for (int k = 0; k < FIN; k++) {
            float w = W[k * HOUT + c];
#pragma unroll
            for (int i = 0; i < NPT; i++) acc[i] += w * xr[i][k];
        }
    } else {
        for (int k = 0; k < FIN; k++) {
            float w = W[k * HOUT + c];
#pragma unroll
            for (int i = 0; i < NPT; i++)
                acc[i] += w * xs[(g * NPT + i) * (FIN + 1) + k];
        }
    }

#pragma unroll
    for (int i = 0; i < NPT; i++) {
        int n = nb0 + g * NPT + i;
        bool ok = (n < n_nodes);
        float h = acc[i];
        if (ok) {
            if (BF16OUT)
                ((__hip_bfloat16*)hout)[(size_t)n * HOUT + c] = __float2bfloat16(h);
            else
                ((float*)hout)[(size_t)n * HOUT + c] = h;
        }
        float pa = h * aSv, pb = h * aDv;
#pragma unroll
        for (int off = 16; off >= 1; off >>= 1) {
            pa += __shfl_xor(pa, off, 32);
            pb += __shfl_xor(pb, off, 32);
        }
        if (ok && cc == 0) { asrc[n * H + head] = pa; adst[n * H + head] = pb; }
    }
}

// ---- CSR build: histogram(+rank) -> 3-phase scan -> atomic-free scatter ----
__global__ void kc_count(const int* __restrict__ ei1, int* __restrict__ cnt,
                         int* __restrict__ rank)
{
    int e = blockIdx.x * 256 + threadIdx.x;
    if (e >= E_EDGES) return;
    rank[e] = atomicAdd(&cnt[ei1[e]], 1);
}

__global__ __launch_bounds__(256) void kc_blocksum(const int* __restrict__ cnt,
                                                   int* __restrict__ bsum)
{
    __shared__ int sd[256];
    const int tid = threadIdx.x;
    int i = blockIdx.x * 256 + tid;
    int v = (i < N_NODES) ? cnt[i] : 0;
    sd[tid] = v;
    __syncthreads();
    for (int off = 128; off >= 1; off >>= 1) {
        if (tid < off) sd[tid] += sd[tid + off];
        __syncthreads();
    }
    if (tid == 0) bsum[blockIdx.x] = sd[0];
}

__global__ __launch_bounds__(256) void kc_scanbsum(const int* __restrict__ bsum,
                                                   int* __restrict__ bofs)
{
    __shared__ int sd[256];
    const int tid = threadIdx.x;
    int v = (tid < SCAN_NB) ? bsum[tid] : 0;
    sd[tid] = v;
    __syncthreads();
    for (int off = 1; off < 256; off <<= 1) {
        int u = (tid >= off) ? sd[tid - off] : 0;
        __syncthreads();
        sd[tid] += u;
        __syncthreads();
    }
    if (tid < SCAN_NB) bofs[tid] = sd[tid] - v;
}

__global__ __launch_bounds__(256) void kc_apply(const int* __restrict__ cnt,
                                                const int* __restrict__ bofs,
                                                int* __restrict__ rowptr)
{
    __shared__ int sd[256];
    const int tid = threadIdx.x;
    int i = blockIdx.x * 256 + tid;
    int v = (i < N_NODES) ? cnt[i] : 0;
    sd[tid] = v;
    __syncthreads();
    for (int off = 1; off < 256; off <<= 1) {
        int u = (tid >= off) ? sd[tid - off] : 0;
        __syncthreads();
        sd[tid] += u;
        __syncthreads();
    }
    int excl = sd[tid] - v + bofs[blockIdx.x];
    if (i < N_NODES) rowptr[i] = excl;
}

__global__ void kc_scatter(const int* __restrict__ ei0, const int* __restrict__ ei1,
                           const int* __restrict__ rowptr, const int* __restrict__ rank,
                           int* __restrict__ srcs)
{
    int e = blockIdx.x * 256 + threadIdx.x;
    if (e >= E_EDGES) return;
    srcs[rowptr[ei1[e]] + rank[e]] = ei0[e];
}

// ---- fused aggregation: online segment-softmax + weighted sum + bias (+ELU) ----
// For TPE==64 (H=4), the node (and thus each src s) is wave-uniform:
// readfirstlane puts gather bases in SGPRs -> global_load with saddr,
// eliminating per-lane 64-bit address arithmetic per edge.
template<int H, int C, bool DO_ELU, bool BF16H>
__global__ __launch_bounds__(256) void k_aggr(
    const float* __restrict__ asrc, const float* __restrict__ adst,
    const void* __restrict__ hbuf, const int* __restrict__ rowptr,
    const int* __restrict__ deg, const int* __restrict__ srcs,
    const float* __restrict__ b, float* __restrict__ outp)
{
    constexpr int HCL = H * C;
    constexpr int TPE = HCL / 2;
    constexpr int NPB = 256 / TPE;
    constexpr bool UNI = (TPE == 64);   // full-wave per node -> s wave-uniform
    const int t = threadIdx.x % TPE;
    const int n = blockIdx.x * NPB + threadIdx.x / TPE;
    if (n >= N_NODES) return;
    const int c0 = 2 * t;
    const int head = c0 / C;
    const float adstv = adst[n * H + head];
    const unsigned* hbu = (const unsigned*)hbuf;
    const float* hbf = (const float*)hbuf;
    float m = lrelu(asrc[n * H + head] + adstv);
    float ssum = 1.f;
    float a0, a1;
    if (BF16H) {
        unsigned u = hbu[(size_t)n * TPE + t];
        a0 = bflo(u); a1 = bfhi(u);
    } else {
        float2 hv = *(const float2*)(hbf + (size_t)n * HCL + c0);
        a0 = hv.x; a1 = hv.y;
    }
    const int base = rowptr[n];
    const int dg = deg[n];
    int i = 0;
    for (; i + 4 <= dg; i += 4) {
        int s0 = srcs[base + i + 0];
        int s1 = srcs[base + i + 1];
        int s2 = srcs[base + i + 2];
        int s3 = srcs[base + i + 3];
        if (UNI) {
            s0 = __builtin_amdgcn_readfirstlane(s0);
            s1 = __builtin_amdgcn_readfirstlane(s1);
            s2 = __builtin_amdgcn_readfirstlane(s2);
            s3 = __builtin_amdgcn_readfirstlane(s3);
        }
        float sc[4];
        sc[0] = lrelu(asrc[s0 * H + head] + adstv);
        sc[1] = lrelu(asrc[s1 * H + head] + adstv);
        sc[2] = lrelu(asrc[s2 * H + head] + adstv);
        sc[3] = lrelu(asrc[s3 * H + head] + adstv);
        float hx[4], hy[4];
        if (BF16H) {
            unsigned u0 = hbu[(size_t)s0 * TPE + t];
            unsigned u1 = hbu[(size_t)s1 * TPE + t];
            unsigned u2 = hbu[(size_t)s2 * TPE + t];
            unsigned u3 = hbu[(size_t)s3 * TPE + t];
            hx[0] = bflo(u0); hy[0] = bfhi(u0);
            hx[1] = bflo(u1); hy[1] = bfhi(u1);
            hx[2] = bflo(u2); hy[2] = bfhi(u2);
            hx[3] = bflo(u3); hy[3] = bfhi(u3);
        } else {
            float2 h0 = *(const float2*)(hbf + (size_t)s0 * HCL + c0);
            float2 h1 = *(const float2*)(hbf + (size_t)s1 * HCL + c0);
            float2 h2 = *(const float2*)(hbf + (size_t)s2 * HCL + c0);
            float2 h3 = *(const float2*)(hbf + (size_t)s3 * HCL + c0);
            hx[0] = h0.x; hy[0] = h0.y;
            hx[1] = h1.x; hy[1] = h1.y;
            hx[2] = h2.x; hy[2] = h2.y;
            hx[3] = h3.x; hy[3] = h3.y;
        }
#pragma unroll
        for (int u = 0; u < 4; u++) {
            float scv = sc[u];
            float ex;
            if (scv > m) {
                float r = __expf(m - scv);
                ssum *= r; a0 *= r; a1 *= r;
                m = scv;
                ex = 1.f;
            } else {
                ex = __expf(scv - m);
            }
            ssum += ex;
            a0 += ex * hx[u];
            a1 += ex * hy[u];
        }
    }
    for (; i < dg; i++) {
        int s = srcs[base + i];
        if (UNI) s = __builtin_amdgcn_readfirstlane(s);
        float sc = lrelu(asrc[s * H + head] + adstv);
        float hxv, hyv;
        if (BF16H) {
            unsigned u = hbu[(size_t)s * TPE + t];
            hxv = bflo(u); hyv = bfhi(u);
        } else {
            float2 hs = *(const float2*)(hbf + (size_t)s * HCL + c0);
            hxv = hs.x; hyv = hs.y;
        }
        float ex;
        if (sc > m) {
            float r = __expf(m - sc);
            ssum *= r; a0 *= r; a1 *= r;
            m = sc;
            ex = 1.f;
        } else {
            ex = __expf(sc - m);
        }
        ssum += ex;
        a0 += ex * hxv;
        a1 += ex * hyv;
    }
    float inv = 1.f / (ssum + 1e-16f);
    float v0 = a0 * inv + b[c0];
    float v1 = a1 * inv + b[c0 + 1];
    if (DO_ELU) {
        v0 = v0 > 0.f ? v0 : __expf(v0) - 1.f;
        v1 = v1 > 0.f ? v1 : __expf(v1) - 1.f;
    }
    *(float2*)(outp + (size_t)n * HCL + c0) = make_float2(v0, v1);
}

// ---- K5a: node-level precompute for MLP layer 1 (bf16 output, unchanged) ----
__global__ __launch_bounds__(256) void k5a_precomp(
    const float* __restrict__ h3, const float* __restrict__ Wm1,
    __hip_bfloat16* __restrict__ Pb)
{
    __shared__ __align__(16) float w[64 * 32];
    __shared__ __align__(16) float hsh[16][33];
    const int tid = threadIdx.x;
    for (int i = tid; i < 64 * 32; i += 256) w[i] = Wm1[i];
    const int nb0 = blockIdx.x * 16;
    for (int idx = tid; idx < 16 * 32; idx += 256) {
        int node = idx / 32, k = idx % 32;
        int gn = nb0 + node;
        hsh[node][k] = (gn < N_NODES) ? h3[gn * 32 + k] : 0.f;
    }
    __syncthreads();
    const int c = tid % 64;
    const int part = c / 32;
    const int j = c % 32;
    for (int ln = tid / 64; ln < 16; ln += 4) {
        int gn = nb0 + ln;
        if (gn >= N_NODES) break;
        float sum = 0.f;
#pragma unroll
        for (int k = 0; k < 32; k++)
            sum += hsh[ln][k] * w[(part * 32 + k) * 32 + j];
        Pb[(size_t)gn * 64 + c] = __float2bfloat16(sum);
    }
}

// ---- K5b: per-edge MLP; scalar weights + packed f4v FMAs (unchanged) ----
__global__ __launch_bounds__(256, 4) void k5b_mlp(
                       const int* __restrict__ ei0, const int* __restrict__ ei1,
                       const __hip_bfloat16* __restrict__ Pb, const float* __restrict__ ea,
                       const float* __restrict__ Wm1, const float* __restrict__ bm1,
                       const float* __restrict__ Wm2, const float* __restrict__ bm2,
                       const float* __restrict__ Wm3, const float* __restrict__ bm3,
                       float* __restrict__ out)
{
    const int e = blockIdx.x * 256 + threadIdx.x;
    if (e >= E_EDGES) return;
    const int s = ei0[e], d = ei1[e];

    const f4v* bm1v = (const f4v*)bm1;
    f4v z1v[8];
#pragma unroll
    for (int q = 0; q < 8; q++) z1v[q] = bm1v[q];

    const f4v* eav = (const f4v*)(ea + (size_t)e * 8);
#pragma unroll
    for (int kq = 0; kq < 2; kq++) {
        f4v v = eav[kq];
#pragma unroll
        for (int r = 0; r < 4; r++) {
            float vr = (r == 0) ? v.x : (r == 1) ? v.y : (r == 2) ? v.z : v.w;
            const f4v* w4 = (const f4v*)(Wm1 + (64 + kq * 4 + r) * 32);
#pragma unroll
            for (int q = 0; q < 8; q++) z1v[q] += w4[q] * vr;
        }
    }
    const uint4* ps4 = (const uint4*)(Pb + (size_t)s * 64);
    const uint4* pd4 = (const uint4*)(Pb + (size_t)d * 64 + 32);
#pragma unroll
    for (int q = 0; q < 4; q++) {
        uint4 a = ps4[q];
        uint4 b = pd4[q];
        f4v pa0 = {bflo(a.x), bfhi(a.x), bflo(a.y), bfhi(a.y)};
        f4v pa1 = {bflo(a.z), bfhi(a.z), bflo(a.w), bfhi(a.w)};
        f4v pb0 = {bflo(b.x), bfhi(b.x), bflo(b.y), bfhi(b.y)};
        f4v pb1 = {bflo(b.z), bfhi(b.z), bflo(b.w), bfhi(b.w)};
        z1v[2 * q + 0] += pa0 + pb0;
        z1v[2 * q + 1] += pa1 + pb1;
    }
#pragma unroll
    for (int q = 0; q < 8; q++) z1v[q] = relu4(z1v[q]);

    const f4v* bm2v = (const f4v*)bm2;
    f4v acc2v[8];
#pragma unroll
    for (int q = 0; q < 8; q++) acc2v[q] = bm2v[q];
#pragma unroll
    for (int k = 0; k < 32; k++) {
        float zk = z1v[k >> 2][k & 3];
        const f4v* w4 = (const f4v*)(Wm2 + k * 32);
#pragma unroll
        for (int q = 0; q < 8; q++) acc2v[q] += w4[q] * zk;
    }
    float z3 = bm3[0];
#pragma unroll
    for (int q = 0; q < 8; q++) {
        const float* w3q = Wm3 + 4 * q;
        float c0 = acc2v[q].x, c1 = acc2v[q].y, c2 = acc2v[q].z, c3 = acc2v[q].w;
        z3 += (c0 > 0.f ? c0 : 0.f) * w3q[0];
        z3 += (c1 > 0.f ? c1 : 0.f) * w3q[1];
        z3 += (c2 > 0.f ? c2 : 0.f) * w3q[2];
        z3 += (c3 > 0.f ? c3 : 0.f) * w3q[3];
    }

    float r = (z3 > 20.f) ? z3 : log1pf(__expf(z3));
    __builtin_nontemporal_store(r, &out[e]);
}

extern "C" void kernel_launch(void* const* d_in, const int* in_sizes, int n_in,
                              void* d_out, int out_size, void* d_ws, size_t ws_size,
                              hipStream_t stream)
{
    const float* x   = (const float*)d_in[0];
    const int*   ei  = (const int*)d_in[1];
    const int*   ei0 = ei;
    const int*   ei1 = ei + E_EDGES;
    const float* ea  = (const float*)d_in[2];
    const float* W1  = (const float*)d_in[3];
    const float* aS1 = (const float*)d_in[4];
    const float* aD1 = (const float*)d_in[5];
    const float* b1  = (const float*)d_in[6];
    const float* W2  = (const float*)d_in[7];
    const float* aS2 = (const float*)d_in[8];
    const float* aD2 = (const float*)d_in[9];
    const float* b2  = (const float*)d_in[10];
    const float* W3  = (const float*)d_in[11];
    const float* aS3 = (const float*)d_in[12];
    const float* aD3 = (const float*)d_in[13];
    const float* b3  = (const float*)d_in[14];
    const float* Wm1 = (const float*)d_in[15];
    const float* bm1 = (const float*)d_in[16];
    const float* Wm2 = (const float*)d_in[17];
    const float* bm2 = (const float*)d_in[18];
    const float* Wm3 = (const float*)d_in[19];
    const float* bm3 = (const float*)d_in[20];

    float* ws = (float*)d_ws;
    float* bufA = ws;                                    // h (bf16 L1/L2, f32 L3) / later Pb
    float* bufB = bufA + (size_t)N_NODES * HC;           // [N,128] layer output (f32)
    float* asrc = bufB + (size_t)N_NODES * HC;           // [N,4]
    float* adst = asrc + (size_t)N_NODES * HEADS;        // [N,4]
    int* cnt    = (int*)(adst + (size_t)N_NODES * HEADS);// [N]
    int* rowptr = cnt + N_NODES;                         // [N]
    int* rank   = rowptr + N_NODES;                      // [E]
    int* srcs   = rank + E_EDGES;                        // [E]
    int* bsum   = srcs + E_EDGES;                        // [SCAN_NB]
    int* bofs   = bsum + 256;                            // [SCAN_NB]

    float* out = (float*)d_out;

    // ---------------- CSR build (once; shared by all 3 layers) ----------------
    hipMemsetAsync(cnt, 0, (size_t)N_NODES * sizeof(int), stream);
    kc_count<<<(E_EDGES + 255) / 256, 256, 0, stream>>>(ei1, cnt, rank);
    kc_blocksum<<<SCAN_NB, 256, 0, stream>>>(cnt, bsum);
    kc_scanbsum<<<1, 256, 0, stream>>>(bsum, bofs);
    kc_apply<<<SCAN_NB, 256, 0, stream>>>(cnt, bofs, rowptr);
    kc_scatter<<<(E_EDGES + 255) / 256, 256, 0, stream>>>(ei0, ei1, rowptr, rank, srcs);

    // ---------------- Layer 1: x[N,16] -> bufB[N,128] (ELU), bf16 h ----------------
    k1_gemm_alpha<NFEAT, HC, HEADS, true><<<(N_NODES + 7) / 8, 256, 0, stream>>>(
        x, W1, aS1, aD1, bufA, asrc, adst, N_NODES);
    k_aggr<HEADS, HID, true, true><<<(N_NODES + 3) / 4, 256, 0, stream>>>(
        asrc, adst, bufA, rowptr, cnt, srcs, b1, bufB);

    // ---------------- Layer 2: bufB[N,128] -> bufB[N,128] (ELU), bf16 h ----------------
    k1_gemm_alpha<HC, HC, HEADS, true><<<(N_NODES + 7) / 8, 256, 0, stream>>>(
        bufB, W2, aS2, aD2, bufA, asrc, adst, N_NODES);
    k_aggr<HEADS, HID, true, true><<<(N_NODES + 3) / 4, 256, 0, stream>>>(
        asrc, adst, bufA, rowptr, cnt, srcs, b2, bufB);

    // ---------------- Layer 3: bufB[N,128] -> bufB[N,32] (no act, H=1), fp32 ----------------
    k1_gemm_alpha<HC, HID, 1, false><<<(N_NODES + 31) / 32, 256, 0, stream>>>(
        bufB, W3, aS3, aD3, bufA, asrc, adst, N_NODES);
    k_aggr<1, HID, false, false><<<(N_NODES + 15) / 16, 256, 0, stream>>>(
        asrc, adst, bufA, rowptr, cnt, srcs, b3, bufB);

    // ---------------- Edge MLP: node precompute (bf16), then per-edge ----------------
    __hip_bfloat16* Pb = (__hip_bfloat16*)bufA;   // bufA free after layer 3
    k5a_precomp<<<(N_NODES + 15) / 16, 256, 0, stream>>>(bufB, Wm1, Pb);
    k5b_mlp<<<(E_EDGES + 255) / 256, 256, 0, stream>>>(
        ei0, ei1, Pb, ea, Wm1, bm1, Wm2, bm2, Wm3, bm3, out);
}

// Round 15
// 305.115 us; speedup vs baseline: 6.7198x; 1.0336x over previous
//
#include <hip/hip_runtime.h>
#include <hip/hip_bf16.h>
#include <math.h>

#define N_NODES 50000
#define E_EDGES 800000
#define NFEAT 16
#define EFEAT 8
#define HID 32
#define HEADS 4
#define HC 128
#define SCAN_NB ((N_NODES + 255) / 256)   // 196

typedef float f4v __attribute__((ext_vector_type(4)));

__device__ __forceinline__ float lrelu(float v) { return v > 0.f ? v : 0.2f * v; }
__device__ __forceinline__ float bflo(unsigned u) { return __uint_as_float(u << 16); }
__device__ __forceinline__ float bfhi(unsigned u) { return __uint_as_float(u & 0xffff0000u); }
__device__ __forceinline__ f4v relu4(f4v v) {
    f4v r;
    r.x = v.x > 0.f ? v.x : 0.f;
    r.y = v.y > 0.f ? v.y : 0.f;
    r.z = v.z > 0.f ? v.z : 0.f;
    r.w = v.w > 0.f ? v.w : 0.f;
    return r;
}

// ---- K1: h = x @ W ; alpha_src/dst = einsum(h, aS/aD) per head (unchanged) ----
template<int FIN, int HOUT, int H, bool BF16OUT>
__global__ void k1_gemm_alpha(const float* __restrict__ x, const float* __restrict__ W,
                              const float* __restrict__ aS, const float* __restrict__ aD,
                              void* __restrict__ hout, float* __restrict__ asrc,
                              float* __restrict__ adst, int n_nodes)
{
    constexpr int GROUPS = 256 / HOUT;
    constexpr int NPT = 4;
    constexpr int NPB = GROUPS * NPT;
    constexpr bool SCALARX = (HOUT >= 64);
    __shared__ float xs[SCALARX ? 1 : NPB * (FIN + 1)];
    const int tid = threadIdx.x;
    const int nb0 = blockIdx.x * NPB;
    const int c = tid % HOUT;
    const int g = tid / HOUT;

    if constexpr (!SCALARX) {
        for (int idx = tid; idx < NPB * FIN; idx += 256) {
            int node = idx / FIN, k = idx % FIN;
            int gn = nb0 + node;
            xs[node * (FIN + 1) + k] = (gn < n_nodes) ? x[(size_t)gn * FIN + k] : 0.f;
        }
        __syncthreads();
    }

    const int head = c / HID;
    const int cc = c % HID;
    const float aSv = aS[head * HID + cc];
    const float aDv = aD[head * HID + cc];
    float acc[NPT];
#pragma unroll
    for (int i = 0; i < NPT; i++) acc[i] = 0.f;

    if constexpr (SCALARX) {
        const float* xr[NPT];
#pragma unroll
        for (int i = 0; i < NPT; i++) {
            int n = nb0 + g * NPT + i;
            unsigned nu = (unsigned)__builtin_amdgcn_readfirstlane(n < n_nodes ? n : 0);
            xr[i] = x + (size_t)nu * FIN;
        }
#pragma unroll 8
        for (int k = 0; k < FIN; k++) {
            float w = W[k * HOUT + c];
#pragma unroll
            for (int i = 0; i < NPT; i++) acc[i] += w * xr[i][k];
        }
    } else {
        for (int k = 0; k < FIN; k++) {
            float w = W[k * HOUT + c];
#pragma unroll
            for (int i = 0; i < NPT; i++)
                acc[i] += w * xs[(g * NPT + i) * (FIN + 1) + k];
        }
    }

#pragma unroll
    for (int i = 0; i < NPT; i++) {
        int n = nb0 + g * NPT + i;
        bool ok = (n < n_nodes);
        float h = acc[i];
        if (ok) {
            if (BF16OUT)
                ((__hip_bfloat16*)hout)[(size_t)n * HOUT + c] = __float2bfloat16(h);
            else
                ((float*)hout)[(size_t)n * HOUT + c] = h;
        }
        float pa = h * aSv, pb = h * aDv;
#pragma unroll
        for (int off = 16; off >= 1; off >>= 1) {
            pa += __shfl_xor(pa, off, 32);
            pb += __shfl_xor(pb, off, 32);
        }
        if (ok && cc == 0) { asrc[n * H + head] = pa; adst[n * H + head] = pb; }
    }
}

// ---- CSR build: histogram(+rank) -> 3-phase scan -> atomic-free scatter ----
__global__ void kc_count(const int* __restrict__ ei1, int* __restrict__ cnt,
                         int* __restrict__ rank)
{
    int e = blockIdx.x * 256 + threadIdx.x;
    if (e >= E_EDGES) return;
    rank[e] = atomicAdd(&cnt[ei1[e]], 1);
}

__global__ __launch_bounds__(256) void kc_blocksum(const int* __restrict__ cnt,
                                                   int* __restrict__ bsum)
{
    __shared__ int sd[256];
    const int tid = threadIdx.x;
    int i = blockIdx.x * 256 + tid;
    int v = (i < N_NODES) ? cnt[i] : 0;
    sd[tid] = v;
    __syncthreads();
    for (int off = 128; off >= 1; off >>= 1) {
        if (tid < off) sd[tid] += sd[tid + off];
        __syncthreads();
    }
    if (tid == 0) bsum[blockIdx.x] = sd[0];
}

__global__ __launch_bounds__(256) void kc_scanbsum(const int* __restrict__ bsum,
                                                   int* __restrict__ bofs)
{
    __shared__ int sd[256];
    const int tid = threadIdx.x;
    int v = (tid < SCAN_NB) ? bsum[tid] : 0;
    sd[tid] = v;
    __syncthreads();
    for (int off = 1; off < 256; off <<= 1) {
        int u = (tid >= off) ? sd[tid - off] : 0;
        __syncthreads();
        sd[tid] += u;
        __syncthreads();
    }
    if (tid < SCAN_NB) bofs[tid] = sd[tid] - v;
}

__global__ __launch_bounds__(256) void kc_apply(const int* __restrict__ cnt,
                                                const int* __restrict__ bofs,
                                                int* __restrict__ rowptr)
{
    __shared__ int sd[256];
    const int tid = threadIdx.x;
    int i = blockIdx.x * 256 + tid;
    int v = (i < N_NODES) ? cnt[i] : 0;
    sd[tid] = v;
    __syncthreads();
    for (int off = 1; off < 256; off <<= 1) {
        int u = (tid >= off) ? sd[tid - off] : 0;
        __syncthreads();
        sd[tid] += u;
        __syncthreads();
    }
    int excl = sd[tid] - v + bofs[blockIdx.x];
    if (i < N_NODES) rowptr[i] = excl;
}

__global__ void kc_scatter(const int* __restrict__ ei0, const int* __restrict__ ei1,
                           const int* __restrict__ rowptr, const int* __restrict__ rank,
                           int* __restrict__ srcs)
{
    int e = blockIdx.x * 256 + threadIdx.x;
    if (e >= E_EDGES) return;
    srcs[rowptr[ei1[e]] + rank[e]] = ei0[e];
}

// ---- fused aggregation: online segment-softmax + weighted sum + bias (+ELU) ----
// UNI (TPE==64): 8-way batched loads with scalar (SGPR) gather bases; the
// online updates stay strictly sequential in edge order (bit-identical).
template<int H, int C, bool DO_ELU, bool BF16H>
__global__ __launch_bounds__(256) void k_aggr(
    const float* __restrict__ asrc, const float* __restrict__ adst,
    const void* __restrict__ hbuf, const int* __restrict__ rowptr,
    const int* __restrict__ deg, const int* __restrict__ srcs,
    const float* __restrict__ b, float* __restrict__ outp)
{
    constexpr int HCL = H * C;
    constexpr int TPE = HCL / 2;
    constexpr int NPB = 256 / TPE;
    constexpr bool UNI = (TPE == 64);
    const int t = threadIdx.x % TPE;
    const int n = blockIdx.x * NPB + threadIdx.x / TPE;
    if (n >= N_NODES) return;
    const int c0 = 2 * t;
    const int head = c0 / C;
    const float adstv = adst[n * H + head];
    const unsigned* hbu = (const unsigned*)hbuf;
    const float* hbf = (const float*)hbuf;
    float m = lrelu(asrc[n * H + head] + adstv);
    float ssum = 1.f;
    float a0, a1;
    if (BF16H) {
        unsigned u = hbu[(size_t)n * TPE + t];
        a0 = bflo(u); a1 = bfhi(u);
    } else {
        float2 hv = *(const float2*)(hbf + (size_t)n * HCL + c0);
        a0 = hv.x; a1 = hv.y;
    }
    const int base = rowptr[n];
    const int dg = deg[n];
    int i = 0;

    if constexpr (UNI && BF16H) {
        // 8-way batched: 8 gathers in flight per wave before the serial updates
        for (; i + 8 <= dg; i += 8) {
            int s[8];
#pragma unroll
            for (int u = 0; u < 8; u++)
                s[u] = __builtin_amdgcn_readfirstlane(srcs[base + i + u]);
            float sc[8];
#pragma unroll
            for (int u = 0; u < 8; u++)
                sc[u] = lrelu(asrc[s[u] * H + head] + adstv);
            unsigned hu[8];
#pragma unroll
            for (int u = 0; u < 8; u++)
                hu[u] = hbu[(size_t)s[u] * TPE + t];
#pragma unroll
            for (int u = 0; u < 8; u++) {
                float scv = sc[u];
                float ex;
                if (scv > m) {
                    float r = __expf(m - scv);
                    ssum *= r; a0 *= r; a1 *= r;
                    m = scv;
                    ex = 1.f;
                } else {
                    ex = __expf(scv - m);
                }
                ssum += ex;
                a0 += ex * bflo(hu[u]);
                a1 += ex * bfhi(hu[u]);
            }
        }
    }

    for (; i + 4 <= dg; i += 4) {
        int s0 = srcs[base + i + 0];
        int s1 = srcs[base + i + 1];
        int s2 = srcs[base + i + 2];
        int s3 = srcs[base + i + 3];
        if (UNI) {
            s0 = __builtin_amdgcn_readfirstlane(s0);
            s1 = __builtin_amdgcn_readfirstlane(s1);
            s2 = __builtin_amdgcn_readfirstlane(s2);
            s3 = __builtin_amdgcn_readfirstlane(s3);
        }
        float sc[4];
        sc[0] = lrelu(asrc[s0 * H + head] + adstv);
        sc[1] = lrelu(asrc[s1 * H + head] + adstv);
        sc[2] = lrelu(asrc[s2 * H + head] + adstv);
        sc[3] = lrelu(asrc[s3 * H + head] + adstv);
        float hx[4], hy[4];
        if (BF16H) {
            unsigned u0 = hbu[(size_t)s0 * TPE + t];
            unsigned u1 = hbu[(size_t)s1 * TPE + t];
            unsigned u2 = hbu[(size_t)s2 * TPE + t];
            unsigned u3 = hbu[(size_t)s3 * TPE + t];
            hx[0] = bflo(u0); hy[0] = bfhi(u0);
            hx[1] = bflo(u1); hy[1] = bfhi(u1);
            hx[2] = bflo(u2); hy[2] = bfhi(u2);
            hx[3] = bflo(u3); hy[3] = bfhi(u3);
        } else {
            float2 h0 = *(const float2*)(hbf + (size_t)s0 * HCL + c0);
            float2 h1 = *(const float2*)(hbf + (size_t)s1 * HCL + c0);
            float2 h2 = *(const float2*)(hbf + (size_t)s2 * HCL + c0);
            float2 h3 = *(const float2*)(hbf + (size_t)s3 * HCL + c0);
            hx[0] = h0.x; hy[0] = h0.y;
            hx[1] = h1.x; hy[1] = h1.y;
            hx[2] = h2.x; hy[2] = h2.y;
            hx[3] = h3.x; hy[3] = h3.y;
        }
#pragma unroll
        for (int u = 0; u < 4; u++) {
            float scv = sc[u];
            float ex;
            if (scv > m) {
                float r = __expf(m - scv);
                ssum *= r; a0 *= r; a1 *= r;
                m = scv;
                ex = 1.f;
            } else {
                ex = __expf(scv - m);
            }
            ssum += ex;
            a0 += ex * hx[u];
            a1 += ex * hy[u];
        }
    }
    for (; i < dg; i++) {
        int s = srcs[base + i];
        if (UNI) s = __builtin_amdgcn_readfirstlane(s);
        float sc = lrelu(asrc[s * H + head] + adstv);
        float hxv, hyv;
        if (BF16H) {
            unsigned u = hbu[(size_t)s * TPE + t];
            hxv = bflo(u); hyv = bfhi(u);
        } else {
            float2 hs = *(const float2*)(hbf + (size_t)s * HCL + c0);
            hxv = hs.x; hyv = hs.y;
        }
        float ex;
        if (sc > m) {
            float r = __expf(m - sc);
            ssum *= r; a0 *= r; a1 *= r;
            m = sc;
            ex = 1.f;
        } else {
            ex = __expf(sc - m);
        }
        ssum += ex;
        a0 += ex * hxv;
        a1 += ex * hyv;
    }
    float inv = 1.f / (ssum + 1e-16f);
    float v0 = a0 * inv + b[c0];
    float v1 = a1 * inv + b[c0 + 1];
    if (DO_ELU) {
        v0 = v0 > 0.f ? v0 : __expf(v0) - 1.f;
        v1 = v1 > 0.f ? v1 : __expf(v1) - 1.f;
    }
    *(float2*)(outp + (size_t)n * HCL + c0) = make_float2(v0, v1);
}

// ---- K5a: node-level precompute for MLP layer 1 (bf16 output, unchanged) ----
__global__ __launch_bounds__(256) void k5a_precomp(
    const float* __restrict__ h3, const float* __restrict__ Wm1,
    __hip_bfloat16* __restrict__ Pb)
{
    __shared__ __align__(16) float w[64 * 32];
    __shared__ __align__(16) float hsh[16][33];
    const int tid = threadIdx.x;
    for (int i = tid; i < 64 * 32; i += 256) w[i] = Wm1[i];
    const int nb0 = blockIdx.x * 16;
    for (int idx = tid; idx < 16 * 32; idx += 256) {
        int node = idx / 32, k = idx % 32;
        int gn = nb0 + node;
        hsh[node][k] = (gn < N_NODES) ? h3[gn * 32 + k] : 0.f;
    }
    __syncthreads();
    const int c = tid % 64;
    const int part = c / 32;
    const int j = c % 32;
    for (int ln = tid / 64; ln < 16; ln += 4) {
        int gn = nb0 + ln;
        if (gn >= N_NODES) break;
        float sum = 0.f;
#pragma unroll
        for (int k = 0; k < 32; k++)
            sum += hsh[ln][k] * w[(part * 32 + k) * 32 + j];
        Pb[(size_t)gn * 64 + c] = __float2bfloat16(sum);
    }
}

// ---- K5b: per-edge MLP; scalar weights + packed f4v FMAs (unchanged) ----
__global__ __launch_bounds__(256, 4) void k5b_mlp(
                       const int* __restrict__ ei0, const int* __restrict__ ei1,
                       const __hip_bfloat16* __restrict__ Pb, const float* __restrict__ ea,
                       const float* __restrict__ Wm1, const float* __restrict__ bm1,
                       const float* __restrict__ Wm2, const float* __restrict__ bm2,
                       const float* __restrict__ Wm3, const float* __restrict__ bm3,
                       float* __restrict__ out)
{
    const int e = blockIdx.x * 256 + threadIdx.x;
    if (e >= E_EDGES) return;
    const int s = ei0[e], d = ei1[e];

    const f4v* bm1v = (const f4v*)bm1;
    f4v z1v[8];
#pragma unroll
    for (int q = 0; q < 8; q++) z1v[q] = bm1v[q];

    const f4v* eav = (const f4v*)(ea + (size_t)e * 8);
#pragma unroll
    for (int kq = 0; kq < 2; kq++) {
        f4v v = eav[kq];
#pragma unroll
        for (int r = 0; r < 4; r++) {
            float vr = (r == 0) ? v.x : (r == 1) ? v.y : (r == 2) ? v.z : v.w;
            const f4v* w4 = (const f4v*)(Wm1 + (64 + kq * 4 + r) * 32);
#pragma unroll
            for (int q = 0; q < 8; q++) z1v[q] += w4[q] * vr;
        }
    }
    const uint4* ps4 = (const uint4*)(Pb + (size_t)s * 64);
    const uint4* pd4 = (const uint4*)(Pb + (size_t)d * 64 + 32);
#pragma unroll
    for (int q = 0; q < 4; q++) {
        uint4 a = ps4[q];
        uint4 b = pd4[q];
        f4v pa0 = {bflo(a.x), bfhi(a.x), bflo(a.y), bfhi(a.y)};
        f4v pa1 = {bflo(a.z), bfhi(a.z), bflo(a.w), bfhi(a.w)};
        f4v pb0 = {bflo(b.x), bfhi(b.x), bflo(b.y), bfhi(b.y)};
        f4v pb1 = {bflo(b.z), bfhi(b.z), bflo(b.w), bfhi(b.w)};
        z1v[2 * q + 0] += pa0 + pb0;
        z1v[2 * q + 1] += pa1 + pb1;
    }
#pragma unroll
    for (int q = 0; q < 8; q++) z1v[q] = relu4(z1v[q]);

    const f4v* bm2v = (const f4v*)bm2;
    f4v acc2v[8];
#pragma unroll
    for (int q = 0; q < 8; q++) acc2v[q] = bm2v[q];
#pragma unroll
    for (int k = 0; k < 32; k++) {
        float zk = z1v[k >> 2][k & 3];
        const f4v* w4 = (const f4v*)(Wm2 + k * 32);
#pragma unroll
        for (int q = 0; q < 8; q++) acc2v[q] += w4[q] * zk;
    }
    float z3 = bm3[0];
#pragma unroll
    for (int q = 0; q < 8; q++) {
        const float* w3q = Wm3 + 4 * q;
        float c0 = acc2v[q].x, c1 = acc2v[q].y, c2 = acc2v[q].z, c3 = acc2v[q].w;
        z3 += (c0 > 0.f ? c0 : 0.f) * w3q[0];
        z3 += (c1 > 0.f ? c1 : 0.f) * w3q[1];
        z3 += (c2 > 0.f ? c2 : 0.f) * w3q[2];
        z3 += (c3 > 0.f ? c3 : 0.f) * w3q[3];
    }

    float r = (z3 > 20.f) ? z3 : log1pf(__expf(z3));
    __builtin_nontemporal_store(r, &out[e]);
}

extern "C" void kernel_launch(void* const* d_in, const int* in_sizes, int n_in,
                              void* d_out, int out_size, void* d_ws, size_t ws_size,
                              hipStream_t stream)
{
    const float* x   = (const float*)d_in[0];
    const int*   ei  = (const int*)d_in[1];
    const int*   ei0 = ei;
    const int*   ei1 = ei + E_EDGES;
    const float* ea  = (const float*)d_in[2];
    const float* W1  = (const float*)d_in[3];
    const float* aS1 = (const float*)d_in[4];
    const float* aD1 = (const float*)d_in[5];
    const float* b1  = (const float*)d_in[6];
    const float* W2  = (const float*)d_in[7];
    const float* aS2 = (const float*)d_in[8];
    const float* aD2 = (const float*)d_in[9];
    const float* b2  = (const float*)d_in[10];
    const float* W3  = (const float*)d_in[11];
    const float* aS3 = (const float*)d_in[12];
    const float* aD3 = (const float*)d_in[13];
    const float* b3  = (const float*)d_in[14];
    const float* Wm1 = (const float*)d_in[15];
    const float* bm1 = (const float*)d_in[16];
    const float* Wm2 = (const float*)d_in[17];
    const float* bm2 = (const float*)d_in[18];
    const float* Wm3 = (const float*)d_in[19];
    const float* bm3 = (const float*)d_in[20];

    float* ws = (float*)d_ws;
    float* bufA = ws;                                    // h (bf16 L1/L2, f32 L3) / later Pb
    float* bufB = bufA + (size_t)N_NODES * HC;           // [N,128] layer output (f32)
    float* asrc = bufB + (size_t)N_NODES * HC;           // [N,4]
    float* adst = asrc + (size_t)N_NODES * HEADS;        // [N,4]
    int* cnt    = (int*)(adst + (size_t)N_NODES * HEADS);// [N]
    int* rowptr = cnt + N_NODES;                         // [N]
    int* rank   = rowptr + N_NODES;                      // [E]
    int* srcs   = rank + E_EDGES;                        // [E]
    int* bsum   = srcs + E_EDGES;                        // [SCAN_NB]
    int* bofs   = bsum + 256;                            // [SCAN_NB]

    float* out = (float*)d_out;

    // ---------------- CSR build (once; shared by all 3 layers) ----------------
    hipMemsetAsync(cnt, 0, (size_t)N_NODES * sizeof(int), stream);
    kc_count<<<(E_EDGES + 255) / 256, 256, 0, stream>>>(ei1, cnt, rank);
    kc_blocksum<<<SCAN_NB, 256, 0, stream>>>(cnt, bsum);
    kc_scanbsum<<<1, 256, 0, stream>>>(bsum, bofs);
    kc_apply<<<SCAN_NB, 256, 0, stream>>>(cnt, bofs, rowptr);
    kc_scatter<<<(E_EDGES + 255) / 256, 256, 0, stream>>>(ei0, ei1, rowptr, rank, srcs);

    // ---------------- Layer 1: x[N,16] -> bufB[N,128] (ELU), bf16 h ----------------
    k1_gemm_alpha<NFEAT, HC, HEADS, true><<<(N_NODES + 7) / 8, 256, 0, stream>>>(
        x, W1, aS1, aD1, bufA, asrc, adst, N_NODES);
    k_aggr<HEADS, HID, true, true><<<(N_NODES + 3) / 4, 256, 0, stream>>>(
        asrc, adst, bufA, rowptr, cnt, srcs, b1, bufB);

    // ---------------- Layer 2: bufB[N,128] -> bufB[N,128] (ELU), bf16 h ----------------
    k1_gemm_alpha<HC, HC, HEADS, true><<<(N_NODES + 7) / 8, 256, 0, stream>>>(
        bufB, W2, aS2, aD2, bufA, asrc, adst, N_NODES);
    k_aggr<HEADS, HID, true, true><<<(N_NODES + 3) / 4, 256, 0, stream>>>(
        asrc, adst, bufA, rowptr, cnt, srcs, b2, bufB);

    // ---------------- Layer 3: bufB[N,128] -> bufB[N,32] (no act, H=1), fp32 ----------------
    k1_gemm_alpha<HC, HID, 1, false><<<(N_NODES + 31) / 32, 256, 0, stream>>>(
        bufB, W3, aS3, aD3, bufA, asrc, adst, N_NODES);
    k_aggr<1, HID, false, false><<<(N_NODES + 15) / 16, 256, 0, stream>>>(
        asrc, adst, bufA, rowptr, cnt, srcs, b3, bufB);

    // ---------------- Edge MLP: node precompute (bf16), then per-edge ----------------
    __hip_bfloat16* Pb = (__hip_bfloat16*)bufA;   // bufA free after layer 3
    k5a_precomp<<<(N_NODES + 15) / 16, 256, 0, stream>>>(bufB, Wm1, Pb);
    k5b_mlp<<<(E_EDGES + 255) / 256, 256, 0, stream>>>(
        ei0, ei1, Pb, ea, Wm1, bm1, Wm2, bm2, Wm3, bm3, out);
}

// Round 16
// 297.050 us; speedup vs baseline: 6.9022x; 1.0272x over previous
//
#include <hip/hip_runtime.h>
#include <hip/hip_bf16.h>
#include <math.h>

#define N_NODES 50000
#define E_EDGES 800000
#define NFEAT 16
#define EFEAT 8
#define HID 32
#define HEADS 4
#define HC 128
#define SCAN_NB ((N_NODES + 255) / 256)   // 196

typedef float f4v __attribute__((ext_vector_type(4)));

__device__ __forceinline__ float lrelu(float v) { return v > 0.f ? v : 0.2f * v; }
__device__ __forceinline__ float bflo(unsigned u) { return __uint_as_float(u << 16); }
__device__ __forceinline__ float bfhi(unsigned u) { return __uint_as_float(u & 0xffff0000u); }
__device__ __forceinline__ f4v relu4(f4v v) {
    f4v r;
    r.x = v.x > 0.f ? v.x : 0.f;
    r.y = v.y > 0.f ? v.y : 0.f;
    r.z = v.z > 0.f ? v.z : 0.f;
    r.w = v.w > 0.f ? v.w : 0.f;
    return r;
}

// ---- K1: h = x @ W ; alpha_src/dst = einsum(h, aS/aD) per head (unchanged) ----
template<int FIN, int HOUT, int H, bool BF16OUT>
__global__ void k1_gemm_alpha(const float* __restrict__ x, const float* __restrict__ W,
                              const float* __restrict__ aS, const float* __restrict__ aD,
                              void* __restrict__ hout, float* __restrict__ asrc,
                              float* __restrict__ adst, int n_nodes)
{
    constexpr int GROUPS = 256 / HOUT;
    constexpr int NPT = 4;
    constexpr int NPB = GROUPS * NPT;
    constexpr bool SCALARX = (HOUT >= 64);
    __shared__ float xs[SCALARX ? 1 : NPB * (FIN + 1)];
    const int tid = threadIdx.x;
    const int nb0 = blockIdx.x * NPB;
    const int c = tid % HOUT;
    const int g = tid / HOUT;

    if constexpr (!SCALARX) {
        for (int idx = tid; idx < NPB * FIN; idx += 256) {
            int node = idx / FIN, k = idx % FIN;
            int gn = nb0 + node;
            xs[node * (FIN + 1) + k] = (gn < n_nodes) ? x[(size_t)gn * FIN + k] : 0.f;
        }
        __syncthreads();
    }

    const int head = c / HID;
    const int cc = c % HID;
    const float aSv = aS[head * HID + cc];
    const float aDv = aD[head * HID + cc];
    float acc[NPT];
#pragma unroll
    for (int i = 0; i < NPT; i++) acc[i] = 0.f;

    if constexpr (SCALARX) {
        const float* xr[NPT];
#pragma unroll
        for (int i = 0; i < NPT; i++) {
            int n = nb0 + g * NPT + i;
            unsigned nu = (unsigned)__builtin_amdgcn_readfirstlane(n < n_nodes ? n : 0);
            xr[i] = x + (size_t)nu * FIN;
        }
#pragma unroll 8
        for (int k = 0; k < FIN; k++) {
            float w = W[k * HOUT + c];
#pragma unroll
            for (int i = 0; i < NPT; i++) acc[i] += w * xr[i][k];
        }
    } else {
        for (int k = 0; k < FIN; k++) {
            float w = W[k * HOUT + c];
#pragma unroll
            for (int i = 0; i < NPT; i++)
                acc[i] += w * xs[(g * NPT + i) * (FIN + 1) + k];
        }
    }

#pragma unroll
    for (int i = 0; i < NPT; i++) {
        int n = nb0 + g * NPT + i;
        bool ok = (n < n_nodes);
        float h = acc[i];
        if (ok) {
            if (BF16OUT)
                ((__hip_bfloat16*)hout)[(size_t)n * HOUT + c] = __float2bfloat16(h);
            else
                ((float*)hout)[(size_t)n * HOUT + c] = h;
        }
        float pa = h * aSv, pb = h * aDv;
#pragma unroll
        for (int off = 16; off >= 1; off >>= 1) {
            pa += __shfl_xor(pa, off, 32);
            pb += __shfl_xor(pb, off, 32);
        }
        if (ok && cc == 0) { asrc[n * H + head] = pa; adst[n * H + head] = pb; }
    }
}

// ---- CSR build: histogram(+rank) -> 3-phase scan -> atomic-free scatter ----
__global__ void kc_count(const int* __restrict__ ei1, int* __restrict__ cnt,
                         int* __restrict__ rank)
{
    int e = blockIdx.x * 256 + threadIdx.x;
    if (e >= E_EDGES) return;
    rank[e] = atomicAdd(&cnt[ei1[e]], 1);
}

__global__ __launch_bounds__(256) void kc_blocksum(const int* __restrict__ cnt,
                                                   int* __restrict__ bsum)
{
    __shared__ int sd[256];
    const int tid = threadIdx.x;
    int i = blockIdx.x * 256 + tid;
    int v = (i < N_NODES) ? cnt[i] : 0;
    sd[tid] = v;
    __syncthreads();
    for (int off = 128; off >= 1; off >>= 1) {
        if (tid < off) sd[tid] += sd[tid + off];
        __syncthreads();
    }
    if (tid == 0) bsum[blockIdx.x] = sd[0];
}

__global__ __launch_bounds__(256) void kc_scanbsum(const int* __restrict__ bsum,
                                                   int* __restrict__ bofs)
{
    __shared__ int sd[256];
    const int tid = threadIdx.x;
    int v = (tid < SCAN_NB) ? bsum[tid] : 0;
    sd[tid] = v;
    __syncthreads();
    for (int off = 1; off < 256; off <<= 1) {
        int u = (tid >= off) ? sd[tid - off] : 0;
        __syncthreads();
        sd[tid] += u;
        __syncthreads();
    }
    if (tid < SCAN_NB) bofs[tid] = sd[tid] - v;
}

__global__ __launch_bounds__(256) void kc_apply(const int* __restrict__ cnt,
                                                const int* __restrict__ bofs,
                                                int* __restrict__ rowptr)
{
    __shared__ int sd[256];
    const int tid = threadIdx.x;
    int i = blockIdx.x * 256 + tid;
    int v = (i < N_NODES) ? cnt[i] : 0;
    sd[tid] = v;
    __syncthreads();
    for (int off = 1; off < 256; off <<= 1) {
        int u = (tid >= off) ? sd[tid - off] : 0;
        __syncthreads();
        sd[tid] += u;
        __syncthreads();
    }
    int excl = sd[tid] - v + bofs[blockIdx.x];
    if (i < N_NODES) rowptr[i] = excl;
}

__global__ void kc_scatter(const int* __restrict__ ei0, const int* __restrict__ ei1,
                           const int* __restrict__ rowptr, const int* __restrict__ rank,
                           int* __restrict__ srcs)
{
    int e = blockIdx.x * 256 + threadIdx.x;
    if (e >= E_EDGES) return;
    srcs[rowptr[ei1[e]] + rank[e]] = ei0[e];
}

// ---- fused aggregation: segment-softmax with FIXED reference point ----
// m0 = self-loop score (no running max). exp(sc - m0) is safely bounded
// (scores are O(1)); the common factor cancels in the final division, so
// the result is algebraically identical to max-shifted softmax.
// This makes every exp independent -> batched exps + 3 independent
// accumulate chains (no serial rescale dependency).
template<int H, int C, bool DO_ELU, bool BF16H>
__global__ __launch_bounds__(256) void k_aggr(
    const float* __restrict__ asrc, const float* __restrict__ adst,
    const void* __restrict__ hbuf, const int* __restrict__ rowptr,
    const int* __restrict__ deg, const int* __restrict__ srcs,
    const float* __restrict__ b, float* __restrict__ outp)
{
    constexpr int HCL = H * C;
    constexpr int TPE = HCL / 2;
    constexpr int NPB = 256 / TPE;
    constexpr bool UNI = (TPE == 64);
    const int t = threadIdx.x % TPE;
    const int n = blockIdx.x * NPB + threadIdx.x / TPE;
    if (n >= N_NODES) return;
    const int c0 = 2 * t;
    const int head = c0 / C;
    const float adstv = adst[n * H + head];
    const unsigned* hbu = (const unsigned*)hbuf;
    const float* hbf = (const float*)hbuf;
    const float m0 = lrelu(asrc[n * H + head] + adstv);   // fixed reference
    float ssum = 1.f;   // self-loop: exp(m0 - m0) = 1
    float a0, a1;
    if (BF16H) {
        unsigned u = hbu[(size_t)n * TPE + t];
        a0 = bflo(u); a1 = bfhi(u);
    } else {
        float2 hv = *(const float2*)(hbf + (size_t)n * HCL + c0);
        a0 = hv.x; a1 = hv.y;
    }
    const int base = rowptr[n];
    const int dg = deg[n];
    int i = 0;

    if constexpr (UNI && BF16H) {
        for (; i + 8 <= dg; i += 8) {
            int s[8];
#pragma unroll
            for (int u = 0; u < 8; u++)
                s[u] = __builtin_amdgcn_readfirstlane(srcs[base + i + u]);
            float ex[8];
#pragma unroll
            for (int u = 0; u < 8; u++)
                ex[u] = __expf(lrelu(asrc[s[u] * H + head] + adstv) - m0);
            unsigned hu[8];
#pragma unroll
            for (int u = 0; u < 8; u++)
                hu[u] = hbu[(size_t)s[u] * TPE + t];
#pragma unroll
            for (int u = 0; u < 8; u++) {
                ssum += ex[u];
                a0 += ex[u] * bflo(hu[u]);
                a1 += ex[u] * bfhi(hu[u]);
            }
        }
    }

    for (; i + 4 <= dg; i += 4) {
        int s0 = srcs[base + i + 0];
        int s1 = srcs[base + i + 1];
        int s2 = srcs[base + i + 2];
        int s3 = srcs[base + i + 3];
        if (UNI) {
            s0 = __builtin_amdgcn_readfirstlane(s0);
            s1 = __builtin_amdgcn_readfirstlane(s1);
            s2 = __builtin_amdgcn_readfirstlane(s2);
            s3 = __builtin_amdgcn_readfirstlane(s3);
        }
        float ex[4];
        ex[0] = __expf(lrelu(asrc[s0 * H + head] + adstv) - m0);
        ex[1] = __expf(lrelu(asrc[s1 * H + head] + adstv) - m0);
        ex[2] = __expf(lrelu(asrc[s2 * H + head] + adstv) - m0);
        ex[3] = __expf(lrelu(asrc[s3 * H + head] + adstv) - m0);
        float hx[4], hy[4];
        if (BF16H) {
            unsigned u0 = hbu[(size_t)s0 * TPE + t];
            unsigned u1 = hbu[(size_t)s1 * TPE + t];
            unsigned u2 = hbu[(size_t)s2 * TPE + t];
            unsigned u3 = hbu[(size_t)s3 * TPE + t];
            hx[0] = bflo(u0); hy[0] = bfhi(u0);
            hx[1] = bflo(u1); hy[1] = bfhi(u1);
            hx[2] = bflo(u2); hy[2] = bfhi(u2);
            hx[3] = bflo(u3); hy[3] = bfhi(u3);
        } else {
            float2 h0 = *(const float2*)(hbf + (size_t)s0 * HCL + c0);
            float2 h1 = *(const float2*)(hbf + (size_t)s1 * HCL + c0);
            float2 h2 = *(const float2*)(hbf + (size_t)s2 * HCL + c0);
            float2 h3 = *(const float2*)(hbf + (size_t)s3 * HCL + c0);
            hx[0] = h0.x; hy[0] = h0.y;
            hx[1] = h1.x; hy[1] = h1.y;
            hx[2] = h2.x; hy[2] = h2.y;
            hx[3] = h3.x; hy[3] = h3.y;
        }
#pragma unroll
        for (int u = 0; u < 4; u++) {
            ssum += ex[u];
            a0 += ex[u] * hx[u];
            a1 += ex[u] * hy[u];
        }
    }
    for (; i < dg; i++) {
        int s = srcs[base + i];
        if (UNI) s = __builtin_amdgcn_readfirstlane(s);
        float ex = __expf(lrelu(asrc[s * H + head] + adstv) - m0);
        float hxv, hyv;
        if (BF16H) {
            unsigned u = hbu[(size_t)s * TPE + t];
            hxv = bflo(u); hyv = bfhi(u);
        } else {
            float2 hs = *(const float2*)(hbf + (size_t)s * HCL + c0);
            hxv = hs.x; hyv = hs.y;
        }
        ssum += ex;
        a0 += ex * hxv;
        a1 += ex * hyv;
    }
    float inv = 1.f / (ssum + 1e-16f);
    float v0 = a0 * inv + b[c0];
    float v1 = a1 * inv + b[c0 + 1];
    if (DO_ELU) {
        v0 = v0 > 0.f ? v0 : __expf(v0) - 1.f;
        v1 = v1 > 0.f ? v1 : __expf(v1) - 1.f;
    }
    *(float2*)(outp + (size_t)n * HCL + c0) = make_float2(v0, v1);
}

// ---- K5a: node-level precompute for MLP layer 1 (bf16 output, unchanged) ----
__global__ __launch_bounds__(256) void k5a_precomp(
    const float* __restrict__ h3, const float* __restrict__ Wm1,
    __hip_bfloat16* __restrict__ Pb)
{
    __shared__ __align__(16) float w[64 * 32];
    __shared__ __align__(16) float hsh[16][33];
    const int tid = threadIdx.x;
    for (int i = tid; i < 64 * 32; i += 256) w[i] = Wm1[i];
    const int nb0 = blockIdx.x * 16;
    for (int idx = tid; idx < 16 * 32; idx += 256) {
        int node = idx / 32, k = idx % 32;
        int gn = nb0 + node;
        hsh[node][k] = (gn < N_NODES) ? h3[gn * 32 + k] : 0.f;
    }
    __syncthreads();
    const int c = tid % 64;
    const int part = c / 32;
    const int j = c % 32;
    for (int ln = tid / 64; ln < 16; ln += 4) {
        int gn = nb0 + ln;
        if (gn >= N_NODES) break;
        float sum = 0.f;
#pragma unroll
        for (int k = 0; k < 32; k++)
            sum += hsh[ln][k] * w[(part * 32 + k) * 32 + j];
        Pb[(size_t)gn * 64 + c] = __float2bfloat16(sum);
    }
}

// ---- K5b: per-edge MLP; scalar weights + packed f4v FMAs (unchanged) ----
__global__ __launch_bounds__(256, 4) void k5b_mlp(
                       const int* __restrict__ ei0, const int* __restrict__ ei1,
                       const __hip_bfloat16* __restrict__ Pb, const float* __restrict__ ea,
                       const float* __restrict__ Wm1, const float* __restrict__ bm1,
                       const float* __restrict__ Wm2, const float* __restrict__ bm2,
                       const float* __restrict__ Wm3, const float* __restrict__ bm3,
                       float* __restrict__ out)
{
    const int e = blockIdx.x * 256 + threadIdx.x;
    if (e >= E_EDGES) return;
    const int s = ei0[e], d = ei1[e];

    const f4v* bm1v = (const f4v*)bm1;
    f4v z1v[8];
#pragma unroll
    for (int q = 0; q < 8; q++) z1v[q] = bm1v[q];

    const f4v* eav = (const f4v*)(ea + (size_t)e * 8);
#pragma unroll
    for (int kq = 0; kq < 2; kq++) {
        f4v v = eav[kq];
#pragma unroll
        for (int r = 0; r < 4; r++) {
            float vr = (r == 0) ? v.x : (r == 1) ? v.y : (r == 2) ? v.z : v.w;
            const f4v* w4 = (const f4v*)(Wm1 + (64 + kq * 4 + r) * 32);
#pragma unroll
            for (int q = 0; q < 8; q++) z1v[q] += w4[q] * vr;
        }
    }
    const uint4* ps4 = (const uint4*)(Pb + (size_t)s * 64);
    const uint4* pd4 = (const uint4*)(Pb + (size_t)d * 64 + 32);
#pragma unroll
    for (int q = 0; q < 4; q++) {
        uint4 a = ps4[q];
        uint4 b = pd4[q];
        f4v pa0 = {bflo(a.x), bfhi(a.x), bflo(a.y), bfhi(a.y)};
        f4v pa1 = {bflo(a.z), bfhi(a.z), bflo(a.w), bfhi(a.w)};
        f4v pb0 = {bflo(b.x), bfhi(b.x), bflo(b.y), bfhi(b.y)};
        f4v pb1 = {bflo(b.z), bfhi(b.z), bflo(b.w), bfhi(b.w)};
        z1v[2 * q + 0] += pa0 + pb0;
        z1v[2 * q + 1] += pa1 + pb1;
    }
#pragma unroll
    for (int q = 0; q < 8; q++) z1v[q] = relu4(z1v[q]);

    const f4v* bm2v = (const f4v*)bm2;
    f4v acc2v[8];
#pragma unroll
    for (int q = 0; q < 8; q++) acc2v[q] = bm2v[q];
#pragma unroll
    for (int k = 0; k < 32; k++) {
        float zk = z1v[k >> 2][k & 3];
        const f4v* w4 = (const f4v*)(Wm2 + k * 32);
#pragma unroll
        for (int q = 0; q < 8; q++) acc2v[q] += w4[q] * zk;
    }
    float z3 = bm3[0];
#pragma unroll
    for (int q = 0; q < 8; q++) {
        const float* w3q = Wm3 + 4 * q;
        float c0 = acc2v[q].x, c1 = acc2v[q].y, c2 = acc2v[q].z, c3 = acc2v[q].w;
        z3 += (c0 > 0.f ? c0 : 0.f) * w3q[0];
        z3 += (c1 > 0.f ? c1 : 0.f) * w3q[1];
        z3 += (c2 > 0.f ? c2 : 0.f) * w3q[2];
        z3 += (c3 > 0.f ? c3 : 0.f) * w3q[3];
    }

    float r = (z3 > 20.f) ? z3 : log1pf(__expf(z3));
    __builtin_nontemporal_store(r, &out[e]);
}

extern "C" void kernel_launch(void* const* d_in, const int* in_sizes, int n_in,
                              void* d_out, int out_size, void* d_ws, size_t ws_size,
                              hipStream_t stream)
{
    const float* x   = (const float*)d_in[0];
    const int*   ei  = (const int*)d_in[1];
    const int*   ei0 = ei;
    const int*   ei1 = ei + E_EDGES;
    const float* ea  = (const float*)d_in[2];
    const float* W1  = (const float*)d_in[3];
    const float* aS1 = (const float*)d_in[4];
    const float* aD1 = (const float*)d_in[5];
    const float* b1  = (const float*)d_in[6];
    const float* W2  = (const float*)d_in[7];
    const float* aS2 = (const float*)d_in[8];
    const float* aD2 = (const float*)d_in[9];
    const float* b2  = (const float*)d_in[10];
    const float* W3  = (const float*)d_in[11];
    const float* aS3 = (const float*)d_in[12];
    const float* aD3 = (const float*)d_in[13];
    const float* b3  = (const float*)d_in[14];
    const float* Wm1 = (const float*)d_in[15];
    const float* bm1 = (const float*)d_in[16];
    const float* Wm2 = (const float*)d_in[17];
    const float* bm2 = (const float*)d_in[18];
    const float* Wm3 = (const float*)d_in[19];
    const float* bm3 = (const float*)d_in[20];

    float* ws = (float*)d_ws;
    float* bufA = ws;                                    // h (bf16 L1/L2, f32 L3) / later Pb
    float* bufB = bufA + (size_t)N_NODES * HC;           // [N,128] layer output (f32)
    float* asrc = bufB + (size_t)N_NODES * HC;           // [N,4]
    float* adst = asrc + (size_t)N_NODES * HEADS;        // [N,4]
    int* cnt    = (int*)(adst + (size_t)N_NODES * HEADS);// [N]
    int* rowptr = cnt + N_NODES;                         // [N]
    int* rank   = rowptr + N_NODES;                      // [E]
    int* srcs   = rank + E_EDGES;                        // [E]
    int* bsum   = srcs + E_EDGES;                        // [SCAN_NB]
    int* bofs   = bsum + 256;                            // [SCAN_NB]

    float* out = (float*)d_out;

    // ---------------- CSR build (once; shared by all 3 layers) ----------------
    hipMemsetAsync(cnt, 0, (size_t)N_NODES * sizeof(int), stream);
    kc_count<<<(E_EDGES + 255) / 256, 256, 0, stream>>>(ei1, cnt, rank);
    kc_blocksum<<<SCAN_NB, 256, 0, stream>>>(cnt, bsum);
    kc_scanbsum<<<1, 256, 0, stream>>>(bsum, bofs);
    kc_apply<<<SCAN_NB, 256, 0, stream>>>(cnt, bofs, rowptr);
    kc_scatter<<<(E_EDGES + 255) / 256, 256, 0, stream>>>(ei0, ei1, rowptr, rank, srcs);

    // ---------------- Layer 1: x[N,16] -> bufB[N,128] (ELU), bf16 h ----------------
    k1_gemm_alpha<NFEAT, HC, HEADS, true><<<(N_NODES + 7) / 8, 256, 0, stream>>>(
        x, W1, aS1, aD1, bufA, asrc, adst, N_NODES);
    k_aggr<HEADS, HID, true, true><<<(N_NODES + 3) / 4, 256, 0, stream>>>(
        asrc, adst, bufA, rowptr, cnt, srcs, b1, bufB);

    // ---------------- Layer 2: bufB[N,128] -> bufB[N,128] (ELU), bf16 h ----------------
    k1_gemm_alpha<HC, HC, HEADS, true><<<(N_NODES + 7) / 8, 256, 0, stream>>>(
        bufB, W2, aS2, aD2, bufA, asrc, adst, N_NODES);
    k_aggr<HEADS, HID, true, true><<<(N_NODES + 3) / 4, 256, 0, stream>>>(
        asrc, adst, bufA, rowptr, cnt, srcs, b2, bufB);

    // ---------------- Layer 3: bufB[N,128] -> bufB[N,32] (no act, H=1), fp32 ----------------
    k1_gemm_alpha<HC, HID, 1, false><<<(N_NODES + 31) / 32, 256, 0, stream>>>(
        bufB, W3, aS3, aD3, bufA, asrc, adst, N_NODES);
    k_aggr<1, HID, false, false><<<(N_NODES + 15) / 16, 256, 0, stream>>>(
        asrc, adst, bufA, rowptr, cnt, srcs, b3, bufB);

    // ---------------- Edge MLP: node precompute (bf16), then per-edge ----------------
    __hip_bfloat16* Pb = (__hip_bfloat16*)bufA;   // bufA free after layer 3
    k5a_precomp<<<(N_NODES + 15) / 16, 256, 0, stream>>>(bufB, Wm1, Pb);
    k5b_mlp<<<(E_EDGES + 255) / 256, 256, 0, stream>>>(
        ei0, ei1, Pb, ea, Wm1, bm1, Wm2, bm2, Wm3, bm3, out);
}